// Round 8
// baseline (1224.213 us; speedup 1.0000x reference)
//
#include <hip/hip_runtime.h>
#include <hip/hip_bf16.h>
#include <stdint.h>
#include <float.h>

// B=64, E=H=512, V=32000, T=20 (lengths[0]=T so max(lengths)==20 always)
#define BB 64
#define EE 512
#define HH 512
#define VV 32000
#define TT 20
#define INV2048 0.00048828125f

typedef _Float16 f16x8 __attribute__((ext_vector_type(8)));
typedef float f32x4 __attribute__((ext_vector_type(4)));

// ---------------- threefry2x32 (JAX-exact, 20 rounds) ----------------
__device__ __host__ __forceinline__ void tf2x32(uint32_t k0, uint32_t k1, uint32_t x0, uint32_t x1,
                                                uint32_t& o0, uint32_t& o1) {
  const uint32_t k2 = k0 ^ k1 ^ 0x1BD11BDAu;
  x0 += k0; x1 += k1;
#define RND(R) { x0 += x1; x1 = (x1 << R) | (x1 >> (32 - R)); x1 ^= x0; }
  RND(13) RND(15) RND(26) RND(6)
  x0 += k1; x1 += k2 + 1u;
  RND(17) RND(29) RND(16) RND(24)
  x0 += k2; x1 += k0 + 2u;
  RND(13) RND(15) RND(26) RND(6)
  x0 += k0; x1 += k1 + 3u;
  RND(17) RND(29) RND(16) RND(24)
  x0 += k1; x1 += k2 + 4u;
  RND(13) RND(15) RND(26) RND(6)
  x0 += k2; x1 += k0 + 5u;
#undef RND
  o0 = x0; o1 = x1;
}

// partitionable-threefry (JAX >= 0.5 default): bits = o0^o1 of tf(key,(0,idx));
// uniform = bitcast(0x3f800000|bits>>9)-1, 0 -> tiny; gumbel = -log(-log(u))
__device__ __forceinline__ float gumbel_for(uint32_t k1t, uint32_t k2t, uint32_t idx) {
  uint32_t o0, o1; tf2x32(k1t, k2t, 0u, idx, o0, o1);
  uint32_t bits = o0 ^ o1;
  uint32_t mant = bits >> 9;
  float f = __uint_as_float(0x3f800000u | mant) - 1.0f;
  float u = mant ? f : 1.1754943508222875e-38f;
  return -logf(-logf(u));
}

struct Part { float bv; int bix; float blog; float m; float s; };

__device__ __forceinline__ void part_combine(Part& P, const Part& Q) {
  if (Q.bv > P.bv || (Q.bv == P.bv && Q.bix < P.bix)) { P.bv = Q.bv; P.bix = Q.bix; P.blog = Q.blog; }
  if (Q.m > P.m) { P.s = P.s * expf(P.m - Q.m) + Q.s; P.m = Q.m; }
  else           { P.s += Q.s * expf(Q.m - P.m); }
}

// ============================================================================
// NEW FAST PATH v3: full-MFMA cell + logits (needs ~76 MB ws)
// ============================================================================

// ---- k_convW2: f32 logits W -> fp16 hi/lo A-frags (K=512, NC=16). grid (500,8) ----
__global__ __launch_bounds__(256) void k_convW2(const float* __restrict__ LW,
                                                _Float16* __restrict__ Wh,
                                                _Float16* __restrict__ Wl) {
  const int bv = blockIdx.x, bk = blockIdx.y;
  const int tx = threadIdx.x;
  __shared__ float lds[64][65];
  #pragma unroll
  for (int r = 0; r < 4; ++r) {
    const int fi = r * 256 + tx;
    const int vl = fi >> 4, k4 = (fi & 15) * 4;
    const float4 v = *(const float4*)(LW + (size_t)(bv * 64 + vl) * HH + bk * 64 + k4);
    lds[vl][k4] = v.x; lds[vl][k4 + 1] = v.y; lds[vl][k4 + 2] = v.z; lds[vl][k4 + 3] = v.w;
  }
  __syncthreads();
  #pragma unroll
  for (int r = 0; r < 2; ++r) {
    const int u = r * 256 + tx;
    const int frag = u >> 6;
    const int vbl = frag >> 1, cl = frag & 1;
    const int lane = u & 63;
    const int m = lane & 15, lh = lane >> 4;
    f16x8 hi, lo;
    #pragma unroll
    for (int j = 0; j < 8; ++j) {
      const float f = lds[vbl * 16 + m][cl * 32 + lh * 8 + j];
      const _Float16 h = (_Float16)f;
      hi[j] = h;
      lo[j] = (_Float16)((f - (float)h) * 2048.0f);
    }
    const size_t o = (((size_t)(bv * 4 + vbl) * 16 + (bk * 2 + cl)) * 64 + lane) * 8;
    *(f16x8*)(Wh + o) = hi;
    *(f16x8*)(Wl + o) = lo;
  }
}

// ---- k_convG: f32 [Wih|Whh] (2048 x 1024) -> fp16 hi/lo A-frags (NC=32). grid (32,16) ----
__global__ __launch_bounds__(256) void k_convG(const float* __restrict__ Wih,
                                               const float* __restrict__ Whh,
                                               _Float16* __restrict__ Gh,
                                               _Float16* __restrict__ Gl) {
  const int bv = blockIdx.x, bk = blockIdx.y;
  const int tx = threadIdx.x;
  __shared__ float lds[64][65];
  const float* src = (bk < 8) ? Wih : Whh;
  const int col = (bk < 8) ? bk * 64 : (bk - 8) * 64;
  #pragma unroll
  for (int r = 0; r < 4; ++r) {
    const int fi = r * 256 + tx;
    const int jl = fi >> 4, k4 = (fi & 15) * 4;
    const float4 v = *(const float4*)(src + (size_t)(bv * 64 + jl) * 512 + col + k4);
    lds[jl][k4] = v.x; lds[jl][k4 + 1] = v.y; lds[jl][k4 + 2] = v.z; lds[jl][k4 + 3] = v.w;
  }
  __syncthreads();
  #pragma unroll
  for (int r = 0; r < 2; ++r) {
    const int u = r * 256 + tx;
    const int frag = u >> 6;
    const int vbl = frag >> 1, cl = frag & 1;
    const int lane = u & 63;
    const int m = lane & 15, lh = lane >> 4;
    f16x8 hi, lo;
    #pragma unroll
    for (int j = 0; j < 8; ++j) {
      const float f = lds[vbl * 16 + m][cl * 32 + lh * 8 + j];
      const _Float16 h = (_Float16)f;
      hi[j] = h;
      lo[j] = (_Float16)((f - (float)h) * 2048.0f);
    }
    const size_t o = (((size_t)(bv * 4 + vbl) * 32 + (bk * 2 + cl)) * 64 + lane) * 8;
    *(f16x8*)(Gh + o) = hi;
    *(f16x8*)(Gl + o) = lo;
  }
}

// ---- k_convX: features [64][512] -> B-frag hi/lo, c=0..15, of buf0 ----
__global__ __launch_bounds__(256) void k_convX(const float* __restrict__ feat,
                                               _Float16* __restrict__ xh,
                                               _Float16* __restrict__ xl) {
  const int t = blockIdx.x * 256 + threadIdx.x;   // 0..32767
  const int b = t >> 9, e = t & 511;
  const float f = feat[t];
  const _Float16 hh = (_Float16)f;
  const _Float16 hl = (_Float16)((f - (float)hh) * 2048.0f);
  const int cc = e >> 5, lane2 = ((e & 31) >> 3) * 16 + (b & 15), j2 = e & 7, nb2 = b >> 4;
  const int fidx = ((cc * 4 + nb2) * 64 + lane2) * 8 + j2;
  xh[fidx] = hh; xl[fidx] = hl;
}

// ---- k_init2: zero cT, done, and buf0's h region (c=16..31) ----
__global__ __launch_bounds__(256) void k_init2(float* __restrict__ cT,
                                               float* __restrict__ xh0f,
                                               float* __restrict__ xl0f,
                                               int* __restrict__ done) {
  const int i = blockIdx.x * 256 + threadIdx.x;   // 32768 threads
  cT[i] = 0.f;
  if (i < 16384) { xh0f[16384 + i] = 0.f; xl0f[16384 + i] = 0.f; }  // halves [32768,65536)
  if (i < BB) done[i] = 0;
}

// ---- k_cell_mfma: fused gates GEMM (MFMA fp16-split) + LSTM update + frag h writes ----
// 32 blocks x 4 waves. Block kt owns k rows [kt*16,kt*16+16); wave g computes gate g
// (A-frag v-tile vb = g*32+kt). B = xb (cur buf, c=0..31 = [x|h]).
__global__ __launch_bounds__(256) void k_cell_mfma(const f16x8* __restrict__ Gh,
                                                   const f16x8* __restrict__ Gl,
                                                   const f16x8* __restrict__ xbh,
                                                   const f16x8* __restrict__ xbl,
                                                   const float* __restrict__ bih,
                                                   const float* __restrict__ bhh,
                                                   float* __restrict__ cT,
                                                   _Float16* __restrict__ hfh,
                                                   _Float16* __restrict__ hfl,
                                                   _Float16* __restrict__ nxh,
                                                   _Float16* __restrict__ nxl) {
  const int kt = blockIdx.x;
  const int g = threadIdx.x >> 6;
  const int lane = threadIdx.x & 63;
  const int vb = g * 32 + kt;
  __shared__ float gl[4][16][64];
  const f32x4 zero = {0.f, 0.f, 0.f, 0.f};
  f32x4 aH[4]  = {zero, zero, zero, zero};
  f32x4 aM1[4] = {zero, zero, zero, zero};
  f32x4 aM2[4] = {zero, zero, zero, zero};
  const size_t wbase = (size_t)vb * 32 * 64 + lane;
  f16x8 whC = Gh[wbase], wlC = Gl[wbase];
  #pragma unroll 4
  for (int c = 0; c < 32; ++c) {
    f16x8 whN, wlN;
    if (c < 31) { whN = Gh[wbase + (c + 1) * 64]; wlN = Gl[wbase + (c + 1) * 64]; }
    #pragma unroll
    for (int nb = 0; nb < 4; ++nb) {
      const f16x8 bh = xbh[(c * 4 + nb) * 64 + lane];
      const f16x8 bl = xbl[(c * 4 + nb) * 64 + lane];
      aH[nb]  = __builtin_amdgcn_mfma_f32_16x16x32_f16(whC, bh, aH[nb], 0, 0, 0);
      aM1[nb] = __builtin_amdgcn_mfma_f32_16x16x32_f16(whC, bl, aM1[nb], 0, 0, 0);
      aM2[nb] = __builtin_amdgcn_mfma_f32_16x16x32_f16(wlC, bh, aM2[nb], 0, 0, 0);
    }
    whC = whN; wlC = wlN;
  }
  // C rows j_local = (lane>>4)*4 + reg, cols b = nb*16 + (lane&15); add biases in f32
  const int jl0 = (lane >> 4) << 2;
  const int j0 = g * 512 + kt * 16 + jl0;
  const float4 bi4 = *(const float4*)(bih + j0);
  const float4 bh4 = *(const float4*)(bhh + j0);
  const float bsum[4] = {bi4.x + bh4.x, bi4.y + bh4.y, bi4.z + bh4.z, bi4.w + bh4.w};
  #pragma unroll
  for (int nb = 0; nb < 4; ++nb) {
    const int bcol = nb * 16 + (lane & 15);
    #pragma unroll
    for (int reg = 0; reg < 4; ++reg) {
      gl[g][jl0 + reg][bcol] = aH[nb][reg] + (aM1[nb][reg] + aM2[nb][reg]) * INV2048 + bsum[reg];
    }
  }
  __syncthreads();
  #pragma unroll
  for (int r = 0; r < 4; ++r) {
    const int idx = r * 256 + threadIdx.x;   // 0..1023 -> (kloc, b)
    const int kloc = idx >> 6, b = idx & 63;
    const float gi = gl[0][kloc][b];
    const float gf = gl[1][kloc][b];
    const float gg = gl[2][kloc][b];
    const float go = gl[3][kloc][b];
    const float ig = 1.f / (1.f + expf(-gi));
    const float fg = 1.f / (1.f + expf(-gf));
    const float gv = tanhf(gg);
    const float og = 1.f / (1.f + expf(-go));
    const int k = kt * 16 + kloc;
    const float c = fg * cT[k * BB + b] + ig * gv;
    cT[k * BB + b] = c;
    const float h = og * tanhf(c);
    const _Float16 hh = (_Float16)h;
    const _Float16 hl = (_Float16)((h - (float)hh) * 2048.0f);
    const int cc = k >> 5, lane2 = ((k & 31) >> 3) * 16 + (b & 15), j2 = k & 7, nb2 = b >> 4;
    const int fidx = ((cc * 4 + nb2) * 64 + lane2) * 8 + j2;
    hfh[fidx] = hh; hfl[fidx] = hl;                                // logits B-frag (c 0..15)
    const int fidx2 = (((16 + cc) * 4 + nb2) * 64 + lane2) * 8 + j2;
    nxh[fidx2] = hh; nxl[fidx2] = hl;                              // next cell input, h region
  }
}

// ---- k_logits4: 500 blocks x 4 waves; prefetched W, split-acc MFMA (r7 proven) ----
__global__ __launch_bounds__(256) void k_logits4(const f16x8* __restrict__ Wh,
                                                 const f16x8* __restrict__ Wl,
                                                 const f16x8* __restrict__ hfh,
                                                 const f16x8* __restrict__ hfl,
                                                 const float* __restrict__ lb,
                                                 uint32_t k1t, uint32_t k2t,
                                                 float4* __restrict__ pf4,
                                                 int* __restrict__ pidx) {
  const int wv = threadIdx.x >> 6;
  const int vt = blockIdx.x * 4 + wv;
  const int lane = threadIdx.x & 63;
  __shared__ float red[4][64][5];
  const f32x4 zero = {0.f, 0.f, 0.f, 0.f};
  f32x4 aH[4]  = {zero, zero, zero, zero};
  f32x4 aM1[4] = {zero, zero, zero, zero};
  f32x4 aM2[4] = {zero, zero, zero, zero};
  const size_t wbase = (size_t)vt * 16 * 64 + lane;
  f16x8 whC = Wh[wbase], wlC = Wl[wbase];
  #pragma unroll 4
  for (int c = 0; c < 16; ++c) {
    f16x8 whN, wlN;
    if (c < 15) { whN = Wh[wbase + (c + 1) * 64]; wlN = Wl[wbase + (c + 1) * 64]; }
    #pragma unroll
    for (int nb = 0; nb < 4; ++nb) {
      const f16x8 bh = hfh[(c * 4 + nb) * 64 + lane];
      const f16x8 bl = hfl[(c * 4 + nb) * 64 + lane];
      aH[nb]  = __builtin_amdgcn_mfma_f32_16x16x32_f16(whC, bh, aH[nb], 0, 0, 0);
      aM1[nb] = __builtin_amdgcn_mfma_f32_16x16x32_f16(whC, bl, aM1[nb], 0, 0, 0);
      aM2[nb] = __builtin_amdgcn_mfma_f32_16x16x32_f16(wlC, bh, aM2[nb], 0, 0, 0);
    }
    whC = whN; wlC = wlN;
  }
  const int v0 = vt * 16 + ((lane >> 4) << 2);
  const float4 bias = *(const float4*)(lb + v0);
  const float bb4[4] = {bias.x, bias.y, bias.z, bias.w};
  Part P[4];
  #pragma unroll
  for (int nb = 0; nb < 4; ++nb) {
    const int b = nb * 16 + (lane & 15);
    float lg = aH[nb][0] + (aM1[nb][0] + aM2[nb][0]) * INV2048 + bb4[0];
    Part p;
    p.bv = lg + gumbel_for(k1t, k2t, (uint32_t)(b * VV + v0));
    p.bix = v0; p.blog = lg; p.m = lg; p.s = 1.0f;
    #pragma unroll
    for (int reg = 1; reg < 4; ++reg) {
      float lg2 = aH[nb][reg] + (aM1[nb][reg] + aM2[nb][reg]) * INV2048 + bb4[reg];
      float pe = lg2 + gumbel_for(k1t, k2t, (uint32_t)(b * VV + v0 + reg));
      if (pe > p.bv) { p.bv = pe; p.bix = v0 + reg; p.blog = lg2; }
      if (lg2 > p.m) { p.s = p.s * expf(p.m - lg2) + 1.f; p.m = lg2; }
      else           { p.s += expf(lg2 - p.m); }
    }
    P[nb] = p;
  }
  #pragma unroll
  for (int msk = 16; msk <= 32; msk <<= 1) {
    #pragma unroll
    for (int nb = 0; nb < 4; ++nb) {
      Part Q;
      Q.bv   = __shfl_xor(P[nb].bv, msk, 64);
      Q.bix  = __shfl_xor(P[nb].bix, msk, 64);
      Q.blog = __shfl_xor(P[nb].blog, msk, 64);
      Q.m    = __shfl_xor(P[nb].m, msk, 64);
      Q.s    = __shfl_xor(P[nb].s, msk, 64);
      part_combine(P[nb], Q);
    }
  }
  if (lane < 16) {
    #pragma unroll
    for (int nb = 0; nb < 4; ++nb) {
      const int b = nb * 16 + lane;
      red[wv][b][0] = P[nb].bv; red[wv][b][1] = __int_as_float(P[nb].bix);
      red[wv][b][2] = P[nb].blog; red[wv][b][3] = P[nb].m; red[wv][b][4] = P[nb].s;
    }
  }
  __syncthreads();
  if (threadIdx.x < 64) {
    const int b = threadIdx.x;
    Part Pc;
    Pc.bv = red[0][b][0]; Pc.bix = __float_as_int(red[0][b][1]); Pc.blog = red[0][b][2];
    Pc.m = red[0][b][3]; Pc.s = red[0][b][4];
    #pragma unroll
    for (int w = 1; w < 4; ++w) {
      Part Q;
      Q.bv = red[w][b][0]; Q.bix = __float_as_int(red[w][b][1]); Q.blog = red[w][b][2];
      Q.m = red[w][b][3]; Q.s = red[w][b][4];
      part_combine(Pc, Q);
    }
    pf4[(size_t)blockIdx.x * BB + b] = make_float4(Pc.bv, Pc.blog, Pc.m, Pc.s);
    pidx[blockIdx.x * BB + b] = Pc.bix;
  }
}

// ---- k_sample3: combine 500 partials, sample, record, embed-gather into B-frag ----
__global__ __launch_bounds__(256) void k_sample3(const float4* __restrict__ pf4,
                                                 const int* __restrict__ pidx,
                                                 const float* __restrict__ embW,
                                                 int* __restrict__ done,
                                                 _Float16* __restrict__ nxh,
                                                 _Float16* __restrict__ nxl,
                                                 float* __restrict__ out,
                                                 int step) {
  const int b = blockIdx.x;
  const int tx = threadIdx.x;
  __shared__ float red[256 * 5];
  __shared__ int stok;
  Part p; p.bv = -FLT_MAX; p.bix = 0x7fffffff; p.blog = 0.f; p.m = -FLT_MAX; p.s = 0.f;
  for (int vt = tx; vt < 500; vt += 256) {
    float4 q = pf4[(size_t)vt * BB + b];
    Part Q; Q.bv = q.x; Q.blog = q.y; Q.m = q.z; Q.s = q.w; Q.bix = pidx[vt * BB + b];
    part_combine(p, Q);
  }
  red[tx * 5 + 0] = p.bv; red[tx * 5 + 1] = __int_as_float(p.bix); red[tx * 5 + 2] = p.blog;
  red[tx * 5 + 3] = p.m;  red[tx * 5 + 4] = p.s;
  __syncthreads();
  for (int st = 128; st > 0; st >>= 1) {
    if (tx < st) {
      const int s0 = tx * 5, s1 = (tx + st) * 5;
      Part P, Q;
      P.bv = red[s0]; P.bix = __float_as_int(red[s0 + 1]); P.blog = red[s0 + 2]; P.m = red[s0 + 3]; P.s = red[s0 + 4];
      Q.bv = red[s1]; Q.bix = __float_as_int(red[s1 + 1]); Q.blog = red[s1 + 2]; Q.m = red[s1 + 3]; Q.s = red[s1 + 4];
      part_combine(P, Q);
      red[s0] = P.bv; red[s0 + 1] = __int_as_float(P.bix); red[s0 + 2] = P.blog; red[s0 + 3] = P.m; red[s0 + 4] = P.s;
    }
    __syncthreads();
  }
  if (tx == 0) {
    const int tok = __float_as_int(red[1]);
    const float blog = red[2], M = red[3], S = red[4];
    const float lp = blog - (M + logf(S));
    const int dn = done[b];
    out[b * TT + step] = dn ? 0.0f : (float)tok;
    out[BB * TT + b * TT + step] = dn ? 0.0f : lp;
    done[b] = dn | (tok == 2);
    stok = tok;
  }
  __syncthreads();
  const int tok = stok;
  for (int e = tx; e < EE; e += 256) {
    const float f = embW[(size_t)tok * EE + e];
    const _Float16 hh = (_Float16)f;
    const _Float16 hl = (_Float16)((f - (float)hh) * 2048.0f);
    const int cc = e >> 5, lane2 = ((e & 31) >> 3) * 16 + (b & 15), j2 = e & 7, nb2 = b >> 4;
    const int fidx = ((cc * 4 + nb2) * 64 + lane2) * 8 + j2;
    nxh[fidx] = hh; nxl[fidx] = hl;
  }
}

// ============================================================================
// FALLBACK PATH (round-7 fast path, ~73 MB) + mid path
// ============================================================================

__global__ __launch_bounds__(256) void k_init(float* __restrict__ hA, float* __restrict__ cT,
                                              int* __restrict__ done) {
  int i = blockIdx.x * 256 + threadIdx.x;
  if (i < HH * BB) { hA[i] = 0.f; cT[i] = 0.f; }
  if (i < BB) done[i] = 0;
}

__global__ __launch_bounds__(256) void k_gates(const float* __restrict__ xin,
                                               const float* __restrict__ hT,
                                               const float* __restrict__ Wih,
                                               const float* __restrict__ Whh,
                                               float* __restrict__ gatesP) {
  const int jt = blockIdx.x;
  const int kc = blockIdx.y;
  const int tx = threadIdx.x;
  __shared__ float a[64][64];
  __shared__ float wj[64][68];
  const int bi = (tx & 15) * 4;
  const int ji = (tx >> 4) * 4;
  float acc[4][4] = {};
  const float* Wsrc = (kc < 4) ? Wih : Whh;
  for (int s = 0; s < 2; ++s) {
    const int kg = kc * 128 + s * 64;
    if (kc < 4) {
      #pragma unroll
      for (int r = 0; r < 4; ++r) {
        int fi = r * 256 + tx;
        int b = fi >> 4, k4 = (fi & 15) * 4;
        const float4 v = *(const float4*)(xin + b * EE + kg + k4);
        a[k4 + 0][b] = v.x; a[k4 + 1][b] = v.y; a[k4 + 2][b] = v.z; a[k4 + 3][b] = v.w;
      }
    } else {
      #pragma unroll
      for (int r = 0; r < 4; ++r) {
        int fi = r * 256 + tx;
        int row = fi >> 4, c4 = (fi & 15) * 4;
        *(float4*)(&a[row][c4]) = *(const float4*)(hT + (kg - 512 + row) * BB + c4);
      }
    }
    const int kcol = kg & 511;
    #pragma unroll
    for (int r = 0; r < 4; ++r) {
      int fi = r * 256 + tx;
      int j = fi >> 4, k4 = (fi & 15) * 4;
      const float4 v = *(const float4*)(Wsrc + (size_t)(jt * 64 + j) * EE + kcol + k4);
      wj[k4 + 0][j] = v.x; wj[k4 + 1][j] = v.y; wj[k4 + 2][j] = v.z; wj[k4 + 3][j] = v.w;
    }
    __syncthreads();
    #pragma unroll 8
    for (int kk = 0; kk < 64; ++kk) {
      const float4 av = *(const float4*)(&a[kk][bi]);
      const float4 wv = *(const float4*)(&wj[kk][ji]);
      const float avx[4] = {av.x, av.y, av.z, av.w};
      const float wvx[4] = {wv.x, wv.y, wv.z, wv.w};
      #pragma unroll
      for (int jj = 0; jj < 4; ++jj)
        #pragma unroll
        for (int bb = 0; bb < 4; ++bb)
          acc[jj][bb] = fmaf(wvx[jj], avx[bb], acc[jj][bb]);
    }
    __syncthreads();
  }
  #pragma unroll
  for (int jj = 0; jj < 4; ++jj) {
    float4 o = make_float4(acc[jj][0], acc[jj][1], acc[jj][2], acc[jj][3]);
    *(float4*)(gatesP + ((size_t)kc * 2048 + jt * 64 + ji + jj) * BB + bi) = o;
  }
}

__global__ __launch_bounds__(256) void k_lstm_update_frag(const float* __restrict__ gatesP,
                                                          const float* __restrict__ b_ih,
                                                          const float* __restrict__ b_hh,
                                                          float* __restrict__ cT,
                                                          float* __restrict__ hT,
                                                          _Float16* __restrict__ hfh,
                                                          _Float16* __restrict__ hfl) {
  const int blk = blockIdx.x;
  const int tx = threadIdx.x;
  const int b = tx & 63;
  const int dk = tx >> 6;
  #pragma unroll
  for (int r = 0; r < 2; ++r) {
    const int k = blk * 8 + dk + r * 4;
    float g[4];
    #pragma unroll
    for (int gi = 0; gi < 4; ++gi) {
      const int j = gi * 512 + k;
      float s = 0.f;
      #pragma unroll
      for (int kc = 0; kc < 8; ++kc) s += gatesP[((size_t)kc * 2048 + j) * BB + b];
      g[gi] = s + b_ih[j] + b_hh[j];
    }
    const float ig = 1.f / (1.f + expf(-g[0]));
    const float fg = 1.f / (1.f + expf(-g[1]));
    const float gg = tanhf(g[2]);
    const float og = 1.f / (1.f + expf(-g[3]));
    const float c = fg * cT[k * BB + b] + ig * gg;
    cT[k * BB + b] = c;
    const float h = og * tanhf(c);
    hT[k * BB + b] = h;
    const _Float16 hh = (_Float16)h;
    const _Float16 hl = (_Float16)((h - (float)hh) * 2048.0f);
    const int cc = k >> 5, kr = k & 31;
    const int lane = (kr >> 3) * 16 + (b & 15), j = kr & 7, nb = b >> 4;
    const int idx = ((cc * 4 + nb) * 64 + lane) * 8 + j;
    hfh[idx] = hh; hfl[idx] = hl;
  }
}

__global__ __launch_bounds__(256) void k_sample2(const float4* __restrict__ pf4,
                                                 const int* __restrict__ pidx,
                                                 const float* __restrict__ embW,
                                                 int* __restrict__ done,
                                                 float* __restrict__ x,
                                                 float* __restrict__ out,
                                                 int step, int nvt) {
  const int b = blockIdx.x;
  const int tx = threadIdx.x;
  __shared__ float red[256 * 5];
  __shared__ int stok;
  Part p; p.bv = -FLT_MAX; p.bix = 0x7fffffff; p.blog = 0.f; p.m = -FLT_MAX; p.s = 0.f;
  for (int vt = tx; vt < nvt; vt += 256) {
    float4 q = pf4[(size_t)vt * BB + b];
    Part Q; Q.bv = q.x; Q.blog = q.y; Q.m = q.z; Q.s = q.w; Q.bix = pidx[vt * BB + b];
    part_combine(p, Q);
  }
  red[tx * 5 + 0] = p.bv; red[tx * 5 + 1] = __int_as_float(p.bix); red[tx * 5 + 2] = p.blog;
  red[tx * 5 + 3] = p.m;  red[tx * 5 + 4] = p.s;
  __syncthreads();
  for (int st = 128; st > 0; st >>= 1) {
    if (tx < st) {
      const int s0 = tx * 5, s1 = (tx + st) * 5;
      Part P, Q;
      P.bv = red[s0]; P.bix = __float_as_int(red[s0 + 1]); P.blog = red[s0 + 2]; P.m = red[s0 + 3]; P.s = red[s0 + 4];
      Q.bv = red[s1]; Q.bix = __float_as_int(red[s1 + 1]); Q.blog = red[s1 + 2]; Q.m = red[s1 + 3]; Q.s = red[s1 + 4];
      part_combine(P, Q);
      red[s0] = P.bv; red[s0 + 1] = __int_as_float(P.bix); red[s0 + 2] = P.blog; red[s0 + 3] = P.m; red[s0 + 4] = P.s;
    }
    __syncthreads();
  }
  if (tx == 0) {
    const int tok = __float_as_int(red[1]);
    const float blog = red[2], M = red[3], S = red[4];
    const float lp = blog - (M + logf(S));
    const int dn = done[b];
    out[b * TT + step] = dn ? 0.0f : (float)tok;
    out[BB * TT + b * TT + step] = dn ? 0.0f : lp;
    done[b] = dn | (tok == 2);
    stok = tok;
  }
  __syncthreads();
  const int tok = stok;
  for (int e = tx; e < EE; e += 256) x[b * EE + e] = embW[(size_t)tok * EE + e];
}

// ---------------- launch ----------------
extern "C" void kernel_launch(void* const* d_in, const int* in_sizes, int n_in,
                              void* d_out, int out_size, void* d_ws, size_t ws_size,
                              hipStream_t stream) {
  const float* features = (const float*)d_in[0];
  const float* embW     = (const float*)d_in[4];
  const float* Wih      = (const float*)d_in[5];
  const float* Whh      = (const float*)d_in[6];
  const float* bih      = (const float*)d_in[7];
  const float* bhh      = (const float*)d_in[8];
  const float* LW       = (const float*)d_in[9];
  const float* lb       = (const float*)d_in[10];
  float* out = (float*)d_out;

  uint32_t keys[TT][2];
  for (int t = 0; t < TT; ++t) tf2x32(0u, 42u, 0u, (uint32_t)t, keys[t][0], keys[t][1]);

  float* ws = (float*)d_ws;

  if (ws_size >= (size_t)80000000) {
    // ---------------- v3: full-MFMA path (~76 MB) ----------------
    float*  cT   = ws;                                   // 32,768 f
    int*    done = (int*)(ws + 32768);                   // 64
    float4* pf4  = (float4*)(ws + 32832);                // 128,000 f
    int*    pidx = (int*)(ws + 160832);                  // 32,000
    _Float16* hfh = (_Float16*)(ws + 192832);            // 32,768 h = 16,384 f
    _Float16* hfl = (_Float16*)(ws + 209216);            // 16,384 f
    float* xb0hf = ws + 225600;                          // 65,536 h = 32,768 f
    float* xb0lf = ws + 258368;
    float* xb1hf = ws + 291136;
    float* xb1lf = ws + 323904;
    _Float16* GhW = (_Float16*)(ws + 356672);            // 2,097,152 h = 1,048,576 f
    _Float16* GlW = (_Float16*)(ws + 1405248);
    _Float16* Whi = (_Float16*)(ws + 2453824);           // 16,384,000 h = 8,192,000 f
    _Float16* Wlo = (_Float16*)(ws + 10645824);          // ends 18,837,824 f (~75.4 MB)

    _Float16* xbh[2] = {(_Float16*)xb0hf, (_Float16*)xb1hf};
    _Float16* xbl[2] = {(_Float16*)xb0lf, (_Float16*)xb1lf};

    k_convW2<<<dim3(500, 8), dim3(256), 0, stream>>>(LW, Whi, Wlo);
    k_convG<<<dim3(32, 16), dim3(256), 0, stream>>>(Wih, Whh, GhW, GlW);
    k_convX<<<dim3(128), dim3(256), 0, stream>>>(features, xbh[0], xbl[0]);
    k_init2<<<dim3(128), dim3(256), 0, stream>>>(cT, xb0hf, xb0lf, done);

    for (int t = 0; t < TT; ++t) {
      const int cur = t & 1, nxt = cur ^ 1;
      k_cell_mfma<<<dim3(32), dim3(256), 0, stream>>>((const f16x8*)GhW, (const f16x8*)GlW,
                                                      (const f16x8*)xbh[cur], (const f16x8*)xbl[cur],
                                                      bih, bhh, cT, hfh, hfl, xbh[nxt], xbl[nxt]);
      k_logits4<<<dim3(500), dim3(256), 0, stream>>>((const f16x8*)Whi, (const f16x8*)Wlo,
                                                     (const f16x8*)hfh, (const f16x8*)hfl,
                                                     lb, keys[t][0], keys[t][1], pf4, pidx);
      k_sample3<<<dim3(64), dim3(256), 0, stream>>>(pf4, pidx, embW, done, xbh[nxt], xbl[nxt], out, t);
    }
  } else {
    // ---------------- r7 fast path fallback (~73 MB) ----------------
    float* hA = ws;
    float* hB = ws + 32768;
    float* cT = ws + 65536;
    float* x  = ws + 98304;
    float*  gatesP = ws + 131072;
    float4* pf4    = (float4*)(ws + 1179648);
    int*    pidx   = (int*)(ws + 1691648);
    int*    done   = (int*)(ws + 1819648);
    _Float16* hfh  = (_Float16*)(ws + 1819712);
    _Float16* hfl  = (_Float16*)(ws + 1836096);
    _Float16* Whi  = (_Float16*)(ws + 1852480);
    _Float16* Wlo  = (_Float16*)(ws + 10044480);

    k_convW2<<<dim3(500, 8), dim3(256), 0, stream>>>(LW, Whi, Wlo);
    k_init<<<dim3(128), dim3(256), 0, stream>>>(hA, cT, done);
    const float* hin = hA;
    float* hout = hB;
    for (int t = 0; t < TT; ++t) {
      const float* xin = (t == 0) ? features : x;
      k_gates<<<dim3(32, 8), dim3(256), 0, stream>>>(xin, hin, Wih, Whh, gatesP);
      k_lstm_update_frag<<<dim3(64), dim3(256), 0, stream>>>(gatesP, bih, bhh, cT, hout, hfh, hfl);
      k_logits4<<<dim3(500), dim3(256), 0, stream>>>((const f16x8*)Whi, (const f16x8*)Wlo,
                                                     (const f16x8*)hfh, (const f16x8*)hfl,
                                                     lb, keys[t][0], keys[t][1], pf4, pidx);
      k_sample2<<<dim3(64), dim3(256), 0, stream>>>(pf4, pidx, embW, done, x, out, t, 500);
      const float* tmp = hout; hout = (float*)hin; hin = tmp;
    }
  }
}

// Round 9
// 1051.244 us; speedup vs baseline: 1.1645x; 1.1645x over previous
//
#include <hip/hip_runtime.h>
#include <hip/hip_bf16.h>
#include <stdint.h>
#include <float.h>

// B=64, E=H=512, V=32000, T=20 (lengths[0]=T so max(lengths)==20 always)
#define BB 64
#define EE 512
#define HH 512
#define VV 32000
#define TT 20
#define INV2048 0.00048828125f

typedef _Float16 f16x8 __attribute__((ext_vector_type(8)));
typedef float f32x4 __attribute__((ext_vector_type(4)));

// ---------------- threefry2x32 (JAX-exact, 20 rounds) ----------------
__device__ __host__ __forceinline__ void tf2x32(uint32_t k0, uint32_t k1, uint32_t x0, uint32_t x1,
                                                uint32_t& o0, uint32_t& o1) {
  const uint32_t k2 = k0 ^ k1 ^ 0x1BD11BDAu;
  x0 += k0; x1 += k1;
#define RND(R) { x0 += x1; x1 = (x1 << R) | (x1 >> (32 - R)); x1 ^= x0; }
  RND(13) RND(15) RND(26) RND(6)
  x0 += k1; x1 += k2 + 1u;
  RND(17) RND(29) RND(16) RND(24)
  x0 += k2; x1 += k0 + 2u;
  RND(13) RND(15) RND(26) RND(6)
  x0 += k0; x1 += k1 + 3u;
  RND(17) RND(29) RND(16) RND(24)
  x0 += k1; x1 += k2 + 4u;
  RND(13) RND(15) RND(26) RND(6)
  x0 += k2; x1 += k0 + 5u;
#undef RND
  o0 = x0; o1 = x1;
}

// partitionable-threefry (JAX >= 0.5 default): bits = o0^o1 of tf(key,(0,idx));
// uniform = bitcast(0x3f800000|bits>>9)-1, 0 -> tiny; gumbel = -log(-log(u))
__device__ __forceinline__ float gumbel_for(uint32_t k1t, uint32_t k2t, uint32_t idx) {
  uint32_t o0, o1; tf2x32(k1t, k2t, 0u, idx, o0, o1);
  uint32_t bits = o0 ^ o1;
  uint32_t mant = bits >> 9;
  float f = __uint_as_float(0x3f800000u | mant) - 1.0f;
  float u = mant ? f : 1.1754943508222875e-38f;
  return -logf(-logf(u));
}

struct Part { float bv; int bix; float blog; float m; float s; };

__device__ __forceinline__ void part_combine(Part& P, const Part& Q) {
  if (Q.bv > P.bv || (Q.bv == P.bv && Q.bix < P.bix)) { P.bv = Q.bv; P.bix = Q.bix; P.blog = Q.blog; }
  if (Q.m > P.m) { P.s = P.s * expf(P.m - Q.m) + Q.s; P.m = Q.m; }
  else           { P.s += Q.s * expf(Q.m - P.m); }
}

// ---------------- K0: init ----------------
__global__ __launch_bounds__(256) void k_init(float* __restrict__ hA, float* __restrict__ cT,
                                              int* __restrict__ done) {
  int i = blockIdx.x * 256 + threadIdx.x;
  if (i < HH * BB) { hA[i] = 0.f; cT[i] = 0.f; }
  if (i < BB) done[i] = 0;
}

// ---------------- k_convW2: f32 logits W -> fp16 hi/lo A-frags. grid (500,8) ----------------
__global__ __launch_bounds__(256) void k_convW2(const float* __restrict__ LW,
                                                _Float16* __restrict__ Wh,
                                                _Float16* __restrict__ Wl) {
  const int bv = blockIdx.x, bk = blockIdx.y;
  const int tx = threadIdx.x;
  __shared__ float lds[64][65];
  #pragma unroll
  for (int r = 0; r < 4; ++r) {
    const int fi = r * 256 + tx;
    const int vl = fi >> 4, k4 = (fi & 15) * 4;
    const float4 v = *(const float4*)(LW + (size_t)(bv * 64 + vl) * HH + bk * 64 + k4);
    lds[vl][k4] = v.x; lds[vl][k4 + 1] = v.y; lds[vl][k4 + 2] = v.z; lds[vl][k4 + 3] = v.w;
  }
  __syncthreads();
  #pragma unroll
  for (int r = 0; r < 2; ++r) {
    const int u = r * 256 + tx;
    const int frag = u >> 6;
    const int vbl = frag >> 1, cl = frag & 1;
    const int lane = u & 63;
    const int m = lane & 15, lh = lane >> 4;
    f16x8 hi, lo;
    #pragma unroll
    for (int j = 0; j < 8; ++j) {
      const float f = lds[vbl * 16 + m][cl * 32 + lh * 8 + j];
      const _Float16 h = (_Float16)f;
      hi[j] = h;
      lo[j] = (_Float16)((f - (float)h) * 2048.0f);
    }
    const size_t o = (((size_t)(bv * 4 + vbl) * 16 + (bk * 2 + cl)) * 64 + lane) * 8;
    *(f16x8*)(Wh + o) = hi;
    *(f16x8*)(Wl + o) = lo;
  }
}

// ---------------- k_gates2: split-k gates GEMM with optional embW[tok] gather ----------------
__global__ __launch_bounds__(256) void k_gates2(const float* __restrict__ xin,   // features (t=0)
                                                const float* __restrict__ embW,
                                                const int* __restrict__ tok,
                                                int use_tok,
                                                const float* __restrict__ hT,
                                                const float* __restrict__ Wih,
                                                const float* __restrict__ Whh,
                                                float* __restrict__ gatesP) {
  const int jt = blockIdx.x;   // 0..31
  const int kc = blockIdx.y;   // 0..7
  const int tx = threadIdx.x;
  __shared__ float a[64][64];
  __shared__ float wj[64][68];
  __shared__ int ltok[64];
  if (tx < 64) ltok[tx] = use_tok ? tok[tx] : 0;
  const int bi = (tx & 15) * 4;
  const int ji = (tx >> 4) * 4;
  float acc[4][4] = {};
  const float* Wsrc = (kc < 4) ? Wih : Whh;
  __syncthreads();
  for (int s = 0; s < 2; ++s) {
    const int kg = kc * 128 + s * 64;
    if (kc < 4) {
      #pragma unroll
      for (int r = 0; r < 4; ++r) {
        int fi = r * 256 + tx;
        int b = fi >> 4, k4 = (fi & 15) * 4;
        const float* rowsrc = use_tok ? (embW + (size_t)ltok[b] * EE) : (xin + (size_t)b * EE);
        const float4 v = *(const float4*)(rowsrc + kg + k4);
        a[k4 + 0][b] = v.x; a[k4 + 1][b] = v.y; a[k4 + 2][b] = v.z; a[k4 + 3][b] = v.w;
      }
    } else {
      #pragma unroll
      for (int r = 0; r < 4; ++r) {
        int fi = r * 256 + tx;
        int row = fi >> 4, c4 = (fi & 15) * 4;
        *(float4*)(&a[row][c4]) = *(const float4*)(hT + (kg - 512 + row) * BB + c4);
      }
    }
    const int kcol = kg & 511;
    #pragma unroll
    for (int r = 0; r < 4; ++r) {
      int fi = r * 256 + tx;
      int j = fi >> 4, k4 = (fi & 15) * 4;
      const float4 v = *(const float4*)(Wsrc + (size_t)(jt * 64 + j) * EE + kcol + k4);
      wj[k4 + 0][j] = v.x; wj[k4 + 1][j] = v.y; wj[k4 + 2][j] = v.z; wj[k4 + 3][j] = v.w;
    }
    __syncthreads();
    #pragma unroll 8
    for (int kk = 0; kk < 64; ++kk) {
      const float4 av = *(const float4*)(&a[kk][bi]);
      const float4 wv = *(const float4*)(&wj[kk][ji]);
      const float avx[4] = {av.x, av.y, av.z, av.w};
      const float wvx[4] = {wv.x, wv.y, wv.z, wv.w};
      #pragma unroll
      for (int jj = 0; jj < 4; ++jj)
        #pragma unroll
        for (int bb = 0; bb < 4; ++bb)
          acc[jj][bb] = fmaf(wvx[jj], avx[bb], acc[jj][bb]);
    }
    __syncthreads();
  }
  #pragma unroll
  for (int jj = 0; jj < 4; ++jj) {
    float4 o = make_float4(acc[jj][0], acc[jj][1], acc[jj][2], acc[jj][3]);
    *(float4*)(gatesP + ((size_t)kc * 2048 + jt * 64 + ji + jj) * BB + bi) = o;
  }
}

// ---------------- k_lstm_update_frag: sum partials + activations + h,c + frag writes ----------------
__global__ __launch_bounds__(256) void k_lstm_update_frag(const float* __restrict__ gatesP,
                                                          const float* __restrict__ b_ih,
                                                          const float* __restrict__ b_hh,
                                                          float* __restrict__ cT,
                                                          float* __restrict__ hT,
                                                          _Float16* __restrict__ hfh,
                                                          _Float16* __restrict__ hfl) {
  const int blk = blockIdx.x;
  const int tx = threadIdx.x;
  const int b = tx & 63;
  const int dk = tx >> 6;
  #pragma unroll
  for (int r = 0; r < 2; ++r) {
    const int k = blk * 8 + dk + r * 4;
    float g[4];
    #pragma unroll
    for (int gi = 0; gi < 4; ++gi) {
      const int j = gi * 512 + k;
      float s = 0.f;
      #pragma unroll
      for (int kc = 0; kc < 8; ++kc) s += gatesP[((size_t)kc * 2048 + j) * BB + b];
      g[gi] = s + b_ih[j] + b_hh[j];
    }
    const float ig = 1.f / (1.f + expf(-g[0]));
    const float fg = 1.f / (1.f + expf(-g[1]));
    const float gg = tanhf(g[2]);
    const float og = 1.f / (1.f + expf(-g[3]));
    const float c = fg * cT[k * BB + b] + ig * gg;
    cT[k * BB + b] = c;
    const float h = og * tanhf(c);
    hT[k * BB + b] = h;
    const _Float16 hh = (_Float16)h;
    const _Float16 hl = (_Float16)((h - (float)hh) * 2048.0f);
    const int cc = k >> 5, kr = k & 31;
    const int lane = (kr >> 3) * 16 + (b & 15), j = kr & 7, nb = b >> 4;
    const int idx = ((cc * 4 + nb) * 64 + lane) * 8 + j;
    hfh[idx] = hh; hfl[idx] = hl;
  }
}

// ---------------- k_logits5: 500 blocks x 4 waves; 4-deep A-ring + 1-deep B prefetch ----------------
__global__ __launch_bounds__(256) void k_logits5(const f16x8* __restrict__ Wh,
                                                 const f16x8* __restrict__ Wl,
                                                 const f16x8* __restrict__ hfh,
                                                 const f16x8* __restrict__ hfl,
                                                 const float* __restrict__ lb,
                                                 uint32_t k1t, uint32_t k2t,
                                                 float4* __restrict__ pf4,
                                                 int* __restrict__ pidx) {
  const int wv = threadIdx.x >> 6;
  const int vt = blockIdx.x * 4 + wv;
  const int lane = threadIdx.x & 63;
  __shared__ float red[4][64][5];
  const f32x4 zero = {0.f, 0.f, 0.f, 0.f};
  f32x4 aH[4]  = {zero, zero, zero, zero};
  f32x4 aM1[4] = {zero, zero, zero, zero};
  f32x4 aM2[4] = {zero, zero, zero, zero};
  const size_t wbase = (size_t)vt * 16 * 64 + lane;
  f16x8 whR[4], wlR[4];
  #pragma unroll
  for (int i = 0; i < 4; ++i) { whR[i] = Wh[wbase + i * 64]; wlR[i] = Wl[wbase + i * 64]; }
  f16x8 bhN[4], blN[4];
  #pragma unroll
  for (int nb = 0; nb < 4; ++nb) { bhN[nb] = hfh[nb * 64 + lane]; blN[nb] = hfl[nb * 64 + lane]; }
  #pragma unroll
  for (int c = 0; c < 16; ++c) {
    const f16x8 whC = whR[c & 3], wlC = wlR[c & 3];
    if (c + 4 < 16) { whR[c & 3] = Wh[wbase + (c + 4) * 64]; wlR[c & 3] = Wl[wbase + (c + 4) * 64]; }
    f16x8 bhC[4], blC[4];
    #pragma unroll
    for (int nb = 0; nb < 4; ++nb) { bhC[nb] = bhN[nb]; blC[nb] = blN[nb]; }
    if (c < 15) {
      #pragma unroll
      for (int nb = 0; nb < 4; ++nb) {
        bhN[nb] = hfh[((c + 1) * 4 + nb) * 64 + lane];
        blN[nb] = hfl[((c + 1) * 4 + nb) * 64 + lane];
      }
    }
    #pragma unroll
    for (int nb = 0; nb < 4; ++nb) {
      aH[nb]  = __builtin_amdgcn_mfma_f32_16x16x32_f16(whC, bhC[nb], aH[nb], 0, 0, 0);
      aM1[nb] = __builtin_amdgcn_mfma_f32_16x16x32_f16(whC, blC[nb], aM1[nb], 0, 0, 0);
      aM2[nb] = __builtin_amdgcn_mfma_f32_16x16x32_f16(wlC, bhC[nb], aM2[nb], 0, 0, 0);
    }
  }
  // epilogue: lane holds C rows v = vt*16 + (lane>>4)*4 + reg, cols b = nb*16 + (lane&15)
  const int v0 = vt * 16 + ((lane >> 4) << 2);
  const float4 bias = *(const float4*)(lb + v0);
  const float bb4[4] = {bias.x, bias.y, bias.z, bias.w};
  Part P[4];
  #pragma unroll
  for (int nb = 0; nb < 4; ++nb) {
    const int b = nb * 16 + (lane & 15);
    float lg = aH[nb][0] + (aM1[nb][0] + aM2[nb][0]) * INV2048 + bb4[0];
    Part p;
    p.bv = lg + gumbel_for(k1t, k2t, (uint32_t)(b * VV + v0));
    p.bix = v0; p.blog = lg; p.m = lg; p.s = 1.0f;
    #pragma unroll
    for (int reg = 1; reg < 4; ++reg) {
      float lg2 = aH[nb][reg] + (aM1[nb][reg] + aM2[nb][reg]) * INV2048 + bb4[reg];
      float pe = lg2 + gumbel_for(k1t, k2t, (uint32_t)(b * VV + v0 + reg));
      if (pe > p.bv) { p.bv = pe; p.bix = v0 + reg; p.blog = lg2; }
      if (lg2 > p.m) { p.s = p.s * expf(p.m - lg2) + 1.f; p.m = lg2; }
      else           { p.s += expf(lg2 - p.m); }
    }
    P[nb] = p;
  }
  #pragma unroll
  for (int msk = 16; msk <= 32; msk <<= 1) {
    #pragma unroll
    for (int nb = 0; nb < 4; ++nb) {
      Part Q;
      Q.bv   = __shfl_xor(P[nb].bv, msk, 64);
      Q.bix  = __shfl_xor(P[nb].bix, msk, 64);
      Q.blog = __shfl_xor(P[nb].blog, msk, 64);
      Q.m    = __shfl_xor(P[nb].m, msk, 64);
      Q.s    = __shfl_xor(P[nb].s, msk, 64);
      part_combine(P[nb], Q);
    }
  }
  if (lane < 16) {
    #pragma unroll
    for (int nb = 0; nb < 4; ++nb) {
      const int b = nb * 16 + lane;
      red[wv][b][0] = P[nb].bv; red[wv][b][1] = __int_as_float(P[nb].bix);
      red[wv][b][2] = P[nb].blog; red[wv][b][3] = P[nb].m; red[wv][b][4] = P[nb].s;
    }
  }
  __syncthreads();
  if (threadIdx.x < 64) {
    const int b = threadIdx.x;
    Part Pc;
    Pc.bv = red[0][b][0]; Pc.bix = __float_as_int(red[0][b][1]); Pc.blog = red[0][b][2];
    Pc.m = red[0][b][3]; Pc.s = red[0][b][4];
    #pragma unroll
    for (int w = 1; w < 4; ++w) {
      Part Q;
      Q.bv = red[w][b][0]; Q.bix = __float_as_int(red[w][b][1]); Q.blog = red[w][b][2];
      Q.m = red[w][b][3]; Q.s = red[w][b][4];
      part_combine(Pc, Q);
    }
    pf4[(size_t)blockIdx.x * BB + b] = make_float4(Pc.bv, Pc.blog, Pc.m, Pc.s);
    pidx[blockIdx.x * BB + b] = Pc.bix;
  }
}

// ---------------- k_sample4: combine 500 partials, sample, record, write tok ----------------
__global__ __launch_bounds__(256) void k_sample4(const float4* __restrict__ pf4,
                                                 const int* __restrict__ pidx,
                                                 int* __restrict__ done,
                                                 int* __restrict__ tokb,
                                                 float* __restrict__ out,
                                                 int step) {
  const int b = blockIdx.x;
  const int tx = threadIdx.x;
  __shared__ float red[256 * 5];
  Part p; p.bv = -FLT_MAX; p.bix = 0x7fffffff; p.blog = 0.f; p.m = -FLT_MAX; p.s = 0.f;
  for (int vt = tx; vt < 500; vt += 256) {
    float4 q = pf4[(size_t)vt * BB + b];
    Part Q; Q.bv = q.x; Q.blog = q.y; Q.m = q.z; Q.s = q.w; Q.bix = pidx[vt * BB + b];
    part_combine(p, Q);
  }
  red[tx * 5 + 0] = p.bv; red[tx * 5 + 1] = __int_as_float(p.bix); red[tx * 5 + 2] = p.blog;
  red[tx * 5 + 3] = p.m;  red[tx * 5 + 4] = p.s;
  __syncthreads();
  for (int st = 128; st > 0; st >>= 1) {
    if (tx < st) {
      const int s0 = tx * 5, s1 = (tx + st) * 5;
      Part P, Q;
      P.bv = red[s0]; P.bix = __float_as_int(red[s0 + 1]); P.blog = red[s0 + 2]; P.m = red[s0 + 3]; P.s = red[s0 + 4];
      Q.bv = red[s1]; Q.bix = __float_as_int(red[s1 + 1]); Q.blog = red[s1 + 2]; Q.m = red[s1 + 3]; Q.s = red[s1 + 4];
      part_combine(P, Q);
      red[s0] = P.bv; red[s0 + 1] = __int_as_float(P.bix); red[s0 + 2] = P.blog; red[s0 + 3] = P.m; red[s0 + 4] = P.s;
    }
    __syncthreads();
  }
  if (tx == 0) {
    const int tok = __float_as_int(red[1]);
    const float blog = red[2], M = red[3], S = red[4];
    const float lp = blog - (M + logf(S));
    const int dn = done[b];
    out[b * TT + step] = dn ? 0.0f : (float)tok;
    out[BB * TT + b * TT + step] = dn ? 0.0f : lp;
    done[b] = dn | (tok == 2);
    tokb[b] = tok;                       // raw tok drives next embedding (matches reference)
  }
}

// ============================================================================
// mid-path fallback (r5 proven) — only used if ws_size < 73 MB (never seen)
// ============================================================================
__global__ __launch_bounds__(256) void k_lstm_update(const float* __restrict__ gatesP,
                                                     const float* __restrict__ b_ih,
                                                     const float* __restrict__ b_hh,
                                                     float* __restrict__ cT,
                                                     float* __restrict__ hT) {
  const int blk = blockIdx.x;
  const int tx = threadIdx.x;
  const int b = tx & 63;
  const int dk = tx >> 6;
  #pragma unroll
  for (int r = 0; r < 2; ++r) {
    const int k = blk * 8 + dk + r * 4;
    float g[4];
    #pragma unroll
    for (int gi = 0; gi < 4; ++gi) {
      const int j = gi * 512 + k;
      float s = 0.f;
      #pragma unroll
      for (int kc = 0; kc < 8; ++kc) s += gatesP[((size_t)kc * 2048 + j) * BB + b];
      g[gi] = s + b_ih[j] + b_hh[j];
    }
    const float ig = 1.f / (1.f + expf(-g[0]));
    const float fg = 1.f / (1.f + expf(-g[1]));
    const float gg = tanhf(g[2]);
    const float og = 1.f / (1.f + expf(-g[3]));
    const float c = fg * cT[k * BB + b] + ig * gg;
    cT[k * BB + b] = c;
    hT[k * BB + b] = og * tanhf(c);
  }
}

__global__ __launch_bounds__(128) void k_logits2(const float* __restrict__ hT,
                                                 const float* __restrict__ LW,
                                                 const float* __restrict__ lb,
                                                 uint32_t k1t, uint32_t k2t,
                                                 float4* __restrict__ pf4,
                                                 int* __restrict__ pidx) {
  const int vt = blockIdx.x;
  const int tx = threadIdx.x;
  __shared__ float lds[5120];
  float* wTs = lds;
  const int vthr = tx & 15;
  const int bthr = tx >> 4;
  const int vi = vthr * 2;
  const int bi = bthr * 8;
  const int vq = tx >> 4;
  const int ks = tx & 15;
  float acc[2][8] = {};
  for (int kt = 0; kt < 8; ++kt) {
    const int kg = kt * 64;
    #pragma unroll
    for (int s = 0; s < 4; ++s) {
      const int kk = ks + 16 * s;
      const size_t rb = (size_t)(vt * 32 + 4 * vq) * HH + kg + kk;
      float w0 = LW[rb];
      float w1 = LW[rb + HH];
      float w2 = LW[rb + 2 * HH];
      float w3 = LW[rb + 3 * HH];
      const int ph = (4 * vq) ^ (4 * (kk & 7));
      *(float4*)&wTs[kk * 32 + ph] = make_float4(w0, w1, w2, w3);
    }
    __syncthreads();
    #pragma unroll 4
    for (int kk = 0; kk < 64; ++kk) {
      const float* hrow = hT + (size_t)(kg + kk) * BB;
      const float4 h0 = *(const float4*)(hrow + bi);
      const float4 h1 = *(const float4*)(hrow + bi + 4);
      const float2 wv = *(const float2*)&wTs[kk * 32 + (vi ^ (4 * (kk & 7)))];
      acc[0][0] = fmaf(wv.x, h0.x, acc[0][0]); acc[0][1] = fmaf(wv.x, h0.y, acc[0][1]);
      acc[0][2] = fmaf(wv.x, h0.z, acc[0][2]); acc[0][3] = fmaf(wv.x, h0.w, acc[0][3]);
      acc[0][4] = fmaf(wv.x, h1.x, acc[0][4]); acc[0][5] = fmaf(wv.x, h1.y, acc[0][5]);
      acc[0][6] = fmaf(wv.x, h1.z, acc[0][6]); acc[0][7] = fmaf(wv.x, h1.w, acc[0][7]);
      acc[1][0] = fmaf(wv.y, h0.x, acc[1][0]); acc[1][1] = fmaf(wv.y, h0.y, acc[1][1]);
      acc[1][2] = fmaf(wv.y, h0.z, acc[1][2]); acc[1][3] = fmaf(wv.y, h0.w, acc[1][3]);
      acc[1][4] = fmaf(wv.y, h1.x, acc[1][4]); acc[1][5] = fmaf(wv.y, h1.y, acc[1][5]);
      acc[1][6] = fmaf(wv.y, h1.z, acc[1][6]); acc[1][7] = fmaf(wv.y, h1.w, acc[1][7]);
    }
    __syncthreads();
  }
  const int v0g = vt * 32 + vi;
  const float bias0 = lb[v0g];
  const float bias1 = lb[v0g + 1];
  float* red = lds;
  #pragma unroll
  for (int bb = 0; bb < 8; ++bb) {
    const int b = bi + bb;
    const float lg0 = acc[0][bb] + bias0;
    const float lg1 = acc[1][bb] + bias1;
    Part p;
    p.bv = lg0 + gumbel_for(k1t, k2t, (uint32_t)(b * VV + v0g));
    p.bix = v0g; p.blog = lg0;
    const float pe1 = lg1 + gumbel_for(k1t, k2t, (uint32_t)(b * VV + v0g + 1));
    if (pe1 > p.bv) { p.bv = pe1; p.bix = v0g + 1; p.blog = lg1; }
    if (lg0 >= lg1) { p.m = lg0; p.s = 1.f + expf(lg1 - lg0); }
    else            { p.m = lg1; p.s = 1.f + expf(lg0 - lg1); }
    const int slot = (b * 16 + vthr) * 5;
    red[slot + 0] = p.bv; red[slot + 1] = __int_as_float(p.bix); red[slot + 2] = p.blog;
    red[slot + 3] = p.m;  red[slot + 4] = p.s;
  }
  __syncthreads();
  if (tx < 64) {
    const int b = tx;
    Part P;
    { const int s0 = (b * 16) * 5;
      P.bv = red[s0]; P.bix = __float_as_int(red[s0 + 1]); P.blog = red[s0 + 2];
      P.m = red[s0 + 3]; P.s = red[s0 + 4]; }
    #pragma unroll
    for (int c = 1; c < 16; ++c) {
      const int s0 = (b * 16 + c) * 5;
      Part Q; Q.bv = red[s0]; Q.bix = __float_as_int(red[s0 + 1]); Q.blog = red[s0 + 2];
      Q.m = red[s0 + 3]; Q.s = red[s0 + 4];
      part_combine(P, Q);
    }
    pf4[(size_t)vt * BB + b] = make_float4(P.bv, P.blog, P.m, P.s);
    pidx[vt * BB + b] = P.bix;
  }
}

__global__ __launch_bounds__(256) void k_sample2(const float4* __restrict__ pf4,
                                                 const int* __restrict__ pidx,
                                                 const float* __restrict__ embW,
                                                 int* __restrict__ done,
                                                 float* __restrict__ x,
                                                 float* __restrict__ out,
                                                 int step, int nvt) {
  const int b = blockIdx.x;
  const int tx = threadIdx.x;
  __shared__ float red[256 * 5];
  __shared__ int stok;
  Part p; p.bv = -FLT_MAX; p.bix = 0x7fffffff; p.blog = 0.f; p.m = -FLT_MAX; p.s = 0.f;
  for (int vt = tx; vt < nvt; vt += 256) {
    float4 q = pf4[(size_t)vt * BB + b];
    Part Q; Q.bv = q.x; Q.blog = q.y; Q.m = q.z; Q.s = q.w; Q.bix = pidx[vt * BB + b];
    part_combine(p, Q);
  }
  red[tx * 5 + 0] = p.bv; red[tx * 5 + 1] = __int_as_float(p.bix); red[tx * 5 + 2] = p.blog;
  red[tx * 5 + 3] = p.m;  red[tx * 5 + 4] = p.s;
  __syncthreads();
  for (int st = 128; st > 0; st >>= 1) {
    if (tx < st) {
      const int s0 = tx * 5, s1 = (tx + st) * 5;
      Part P, Q;
      P.bv = red[s0]; P.bix = __float_as_int(red[s0 + 1]); P.blog = red[s0 + 2]; P.m = red[s0 + 3]; P.s = red[s0 + 4];
      Q.bv = red[s1]; Q.bix = __float_as_int(red[s1 + 1]); Q.blog = red[s1 + 2]; Q.m = red[s1 + 3]; Q.s = red[s1 + 4];
      part_combine(P, Q);
      red[s0] = P.bv; red[s0 + 1] = __int_as_float(P.bix); red[s0 + 2] = P.blog; red[s0 + 3] = P.m; red[s0 + 4] = P.s;
    }
    __syncthreads();
  }
  if (tx == 0) {
    const int tok = __float_as_int(red[1]);
    const float blog = red[2], M = red[3], S = red[4];
    const float lp = blog - (M + logf(S));
    const int dn = done[b];
    out[b * TT + step] = dn ? 0.0f : (float)tok;
    out[BB * TT + b * TT + step] = dn ? 0.0f : lp;
    done[b] = dn | (tok == 2);
    stok = tok;
  }
  __syncthreads();
  const int tok = stok;
  for (int e = tx; e < EE; e += 256) x[b * EE + e] = embW[(size_t)tok * EE + e];
}

// ---------------- launch ----------------
extern "C" void kernel_launch(void* const* d_in, const int* in_sizes, int n_in,
                              void* d_out, int out_size, void* d_ws, size_t ws_size,
                              hipStream_t stream) {
  const float* features = (const float*)d_in[0];
  const float* embW     = (const float*)d_in[4];
  const float* Wih      = (const float*)d_in[5];
  const float* Whh      = (const float*)d_in[6];
  const float* bih      = (const float*)d_in[7];
  const float* bhh      = (const float*)d_in[8];
  const float* LW       = (const float*)d_in[9];
  const float* lb       = (const float*)d_in[10];
  float* out = (float*)d_out;

  uint32_t keys[TT][2];
  for (int t = 0; t < TT; ++t) tf2x32(0u, 42u, 0u, (uint32_t)t, keys[t][0], keys[t][1]);

  float* ws = (float*)d_ws;

  if (ws_size >= (size_t)73000000) {
    // ---------------- fast path (r7 structure + logits5/sample4/tok-gather) ----------------
    float* hA = ws;                                     // 32768
    float* hB = ws + 32768;
    float* cT = ws + 65536;
    int*   tokb = (int*)(ws + 98304);                   // 64 (old x slot)
    float*  gatesP = ws + 131072;                       // 1,048,576 f
    float4* pf4    = (float4*)(ws + 1179648);
    int*    pidx   = (int*)(ws + 1691648);
    int*    done   = (int*)(ws + 1819648);
    _Float16* hfh  = (_Float16*)(ws + 1819712);
    _Float16* hfl  = (_Float16*)(ws + 1836096);
    _Float16* Whi  = (_Float16*)(ws + 1852480);
    _Float16* Wlo  = (_Float16*)(ws + 10044480);

    k_convW2<<<dim3(500, 8), dim3(256), 0, stream>>>(LW, Whi, Wlo);
    k_init<<<dim3(128), dim3(256), 0, stream>>>(hA, cT, done);
    const float* hin = hA;
    float* hout = hB;
    for (int t = 0; t < TT; ++t) {
      k_gates2<<<dim3(32, 8), dim3(256), 0, stream>>>(features, embW, tokb, (t > 0) ? 1 : 0,
                                                      hin, Wih, Whh, gatesP);
      k_lstm_update_frag<<<dim3(64), dim3(256), 0, stream>>>(gatesP, bih, bhh, cT, hout, hfh, hfl);
      k_logits5<<<dim3(500), dim3(256), 0, stream>>>((const f16x8*)Whi, (const f16x8*)Wlo,
                                                     (const f16x8*)hfh, (const f16x8*)hfl,
                                                     lb, keys[t][0], keys[t][1], pf4, pidx);
      k_sample4<<<dim3(64), dim3(256), 0, stream>>>(pf4, pidx, done, tokb, out, t);
      const float* tmp = hout; hout = (float*)hin; hin = tmp;
    }
  } else {
    // ---------------- mid path (r5 proven, ~6.4 MB) ----------------
    float* hA = ws;
    float* hB = ws + 32768;
    float* cT = ws + 65536;
    float* x  = ws + 98304;
    float*  gatesP = ws + 131072;
    float4* pf4    = (float4*)(ws + 131072 + 1048576);
    int*    pidx   = (int*)(ws + 131072 + 1048576 + 256000);
    int*    done   = (int*)(ws + 131072 + 1048576 + 256000 + 64000);

    k_init<<<dim3(128), dim3(256), 0, stream>>>(hA, cT, done);
    const float* hin = hA;
    float* hout = hB;
    for (int t = 0; t < TT; ++t) {
      const float* xin = (t == 0) ? features : x;
      k_gates2<<<dim3(32, 8), dim3(256), 0, stream>>>(xin, embW, done /*unused*/, 0,
                                                      hin, Wih, Whh, gatesP);
      k_lstm_update<<<dim3(64), dim3(256), 0, stream>>>(gatesP, bih, bhh, cT, hout);
      k_logits2<<<dim3(1000), dim3(128), 0, stream>>>(hout, LW, lb, keys[t][0], keys[t][1], pf4, pidx);
      k_sample2<<<dim3(64), dim3(256), 0, stream>>>(pf4, pidx, embW, done, x, out, t, 1000);
      const float* tmp = hout; hout = (float*)hin; hin = tmp;
    }
  }
}

// Round 10
// 1026.669 us; speedup vs baseline: 1.1924x; 1.0239x over previous
//
#include <hip/hip_runtime.h>
#include <hip/hip_bf16.h>
#include <stdint.h>
#include <float.h>

// B=64, E=H=512, V=32000, T=20 (lengths[0]=T so max(lengths)==20 always)
#define BB 64
#define EE 512
#define HH 512
#define VV 32000
#define TT 20
#define INV2048 0.00048828125f

typedef _Float16 f16x8 __attribute__((ext_vector_type(8)));
typedef float f32x4 __attribute__((ext_vector_type(4)));

// ---------------- threefry2x32 (JAX-exact, 20 rounds) ----------------
__device__ __host__ __forceinline__ void tf2x32(uint32_t k0, uint32_t k1, uint32_t x0, uint32_t x1,
                                                uint32_t& o0, uint32_t& o1) {
  const uint32_t k2 = k0 ^ k1 ^ 0x1BD11BDAu;
  x0 += k0; x1 += k1;
#define RND(R) { x0 += x1; x1 = (x1 << R) | (x1 >> (32 - R)); x1 ^= x0; }
  RND(13) RND(15) RND(26) RND(6)
  x0 += k1; x1 += k2 + 1u;
  RND(17) RND(29) RND(16) RND(24)
  x0 += k2; x1 += k0 + 2u;
  RND(13) RND(15) RND(26) RND(6)
  x0 += k0; x1 += k1 + 3u;
  RND(17) RND(29) RND(16) RND(24)
  x0 += k1; x1 += k2 + 4u;
  RND(13) RND(15) RND(26) RND(6)
  x0 += k2; x1 += k0 + 5u;
#undef RND
  o0 = x0; o1 = x1;
}

// partitionable-threefry (JAX >= 0.5 default): bits = o0^o1 of tf(key,(0,idx));
// uniform = bitcast(0x3f800000|bits>>9)-1, 0 -> tiny; gumbel = -log(-log(u))
__device__ __forceinline__ float gumbel_for(uint32_t k1t, uint32_t k2t, uint32_t idx) {
  uint32_t o0, o1; tf2x32(k1t, k2t, 0u, idx, o0, o1);
  uint32_t bits = o0 ^ o1;
  uint32_t mant = bits >> 9;
  float f = __uint_as_float(0x3f800000u | mant) - 1.0f;
  float u = mant ? f : 1.1754943508222875e-38f;
  return -logf(-logf(u));
}

struct Part { float bv; int bix; float blog; float m; float s; };

__device__ __forceinline__ void part_combine(Part& P, const Part& Q) {
  if (Q.bv > P.bv || (Q.bv == P.bv && Q.bix < P.bix)) { P.bv = Q.bv; P.bix = Q.bix; P.blog = Q.blog; }
  if (Q.m > P.m) { P.s = P.s * expf(P.m - Q.m) + Q.s; P.m = Q.m; }
  else           { P.s += Q.s * expf(Q.m - P.m); }
}

// ---------------- K0: init ----------------
__global__ __launch_bounds__(256) void k_init(float* __restrict__ hA, float* __restrict__ cT,
                                              int* __restrict__ done) {
  int i = blockIdx.x * 256 + threadIdx.x;
  if (i < HH * BB) { hA[i] = 0.f; cT[i] = 0.f; }
  if (i < BB) done[i] = 0;
}

// ---------------- k_convW2: f32 logits W -> fp16 hi/lo A-frags. grid (500,8) ----------------
__global__ __launch_bounds__(256) void k_convW2(const float* __restrict__ LW,
                                                _Float16* __restrict__ Wh,
                                                _Float16* __restrict__ Wl) {
  const int bv = blockIdx.x, bk = blockIdx.y;
  const int tx = threadIdx.x;
  __shared__ float lds[64][65];
  #pragma unroll
  for (int r = 0; r < 4; ++r) {
    const int fi = r * 256 + tx;
    const int vl = fi >> 4, k4 = (fi & 15) * 4;
    const float4 v = *(const float4*)(LW + (size_t)(bv * 64 + vl) * HH + bk * 64 + k4);
    lds[vl][k4] = v.x; lds[vl][k4 + 1] = v.y; lds[vl][k4 + 2] = v.z; lds[vl][k4 + 3] = v.w;
  }
  __syncthreads();
  #pragma unroll
  for (int r = 0; r < 2; ++r) {
    const int u = r * 256 + tx;
    const int frag = u >> 6;
    const int vbl = frag >> 1, cl = frag & 1;
    const int lane = u & 63;
    const int m = lane & 15, lh = lane >> 4;
    f16x8 hi, lo;
    #pragma unroll
    for (int j = 0; j < 8; ++j) {
      const float f = lds[vbl * 16 + m][cl * 32 + lh * 8 + j];
      const _Float16 h = (_Float16)f;
      hi[j] = h;
      lo[j] = (_Float16)((f - (float)h) * 2048.0f);
    }
    const size_t o = (((size_t)(bv * 4 + vbl) * 16 + (bk * 2 + cl)) * 64 + lane) * 8;
    *(f16x8*)(Wh + o) = hi;
    *(f16x8*)(Wl + o) = lo;
  }
}

// ---------------- k_gates: split-k gates GEMM (r7 proven) ----------------
__global__ __launch_bounds__(256) void k_gates(const float* __restrict__ xin,  // [64][512] b-major
                                               const float* __restrict__ hT,   // [512][64]
                                               const float* __restrict__ Wih,
                                               const float* __restrict__ Whh,
                                               float* __restrict__ gatesP) {
  const int jt = blockIdx.x;   // 0..31
  const int kc = blockIdx.y;   // 0..7
  const int tx = threadIdx.x;
  __shared__ float a[64][64];
  __shared__ float wj[64][68];
  const int bi = (tx & 15) * 4;
  const int ji = (tx >> 4) * 4;
  float acc[4][4] = {};
  const float* Wsrc = (kc < 4) ? Wih : Whh;
  for (int s = 0; s < 2; ++s) {
    const int kg = kc * 128 + s * 64;
    if (kc < 4) {
      #pragma unroll
      for (int r = 0; r < 4; ++r) {
        int fi = r * 256 + tx;
        int b = fi >> 4, k4 = (fi & 15) * 4;
        const float4 v = *(const float4*)(xin + b * EE + kg + k4);
        a[k4 + 0][b] = v.x; a[k4 + 1][b] = v.y; a[k4 + 2][b] = v.z; a[k4 + 3][b] = v.w;
      }
    } else {
      #pragma unroll
      for (int r = 0; r < 4; ++r) {
        int fi = r * 256 + tx;
        int row = fi >> 4, c4 = (fi & 15) * 4;
        *(float4*)(&a[row][c4]) = *(const float4*)(hT + (kg - 512 + row) * BB + c4);
      }
    }
    const int kcol = kg & 511;
    #pragma unroll
    for (int r = 0; r < 4; ++r) {
      int fi = r * 256 + tx;
      int j = fi >> 4, k4 = (fi & 15) * 4;
      const float4 v = *(const float4*)(Wsrc + (size_t)(jt * 64 + j) * EE + kcol + k4);
      wj[k4 + 0][j] = v.x; wj[k4 + 1][j] = v.y; wj[k4 + 2][j] = v.z; wj[k4 + 3][j] = v.w;
    }
    __syncthreads();
    #pragma unroll 8
    for (int kk = 0; kk < 64; ++kk) {
      const float4 av = *(const float4*)(&a[kk][bi]);
      const float4 wv = *(const float4*)(&wj[kk][ji]);
      const float avx[4] = {av.x, av.y, av.z, av.w};
      const float wvx[4] = {wv.x, wv.y, wv.z, wv.w};
      #pragma unroll
      for (int jj = 0; jj < 4; ++jj)
        #pragma unroll
        for (int bb = 0; bb < 4; ++bb)
          acc[jj][bb] = fmaf(wvx[jj], avx[bb], acc[jj][bb]);
    }
    __syncthreads();
  }
  #pragma unroll
  for (int jj = 0; jj < 4; ++jj) {
    float4 o = make_float4(acc[jj][0], acc[jj][1], acc[jj][2], acc[jj][3]);
    *(float4*)(gatesP + ((size_t)kc * 2048 + jt * 64 + ji + jj) * BB + bi) = o;
  }
}

// ---------------- k_lstm_update_frag: sum partials + activations + h,c + frag writes ----------------
__global__ __launch_bounds__(256) void k_lstm_update_frag(const float* __restrict__ gatesP,
                                                          const float* __restrict__ b_ih,
                                                          const float* __restrict__ b_hh,
                                                          float* __restrict__ cT,
                                                          float* __restrict__ hT,
                                                          _Float16* __restrict__ hfh,
                                                          _Float16* __restrict__ hfl) {
  const int blk = blockIdx.x;
  const int tx = threadIdx.x;
  const int b = tx & 63;
  const int dk = tx >> 6;
  #pragma unroll
  for (int r = 0; r < 2; ++r) {
    const int k = blk * 8 + dk + r * 4;
    float g[4];
    #pragma unroll
    for (int gi = 0; gi < 4; ++gi) {
      const int j = gi * 512 + k;
      float s = 0.f;
      #pragma unroll
      for (int kc = 0; kc < 8; ++kc) s += gatesP[((size_t)kc * 2048 + j) * BB + b];
      g[gi] = s + b_ih[j] + b_hh[j];
    }
    const float ig = 1.f / (1.f + expf(-g[0]));
    const float fg = 1.f / (1.f + expf(-g[1]));
    const float gg = tanhf(g[2]);
    const float og = 1.f / (1.f + expf(-g[3]));
    const float c = fg * cT[k * BB + b] + ig * gg;
    cT[k * BB + b] = c;
    const float h = og * tanhf(c);
    hT[k * BB + b] = h;
    const _Float16 hh = (_Float16)h;
    const _Float16 hl = (_Float16)((h - (float)hh) * 2048.0f);
    const int cc = k >> 5, kr = k & 31;
    const int lane = (kr >> 3) * 16 + (b & 15), j = kr & 7, nb = b >> 4;
    const int idx = ((cc * 4 + nb) * 64 + lane) * 8 + j;
    hfh[idx] = hh; hfl[idx] = hl;
  }
}

// ---------------- k_logits4b: 500 blocks x 4 waves; 2-deep A-prefetch (r7 + one change) ----------------
__global__ __launch_bounds__(256) void k_logits4b(const f16x8* __restrict__ Wh,
                                                  const f16x8* __restrict__ Wl,
                                                  const f16x8* __restrict__ hfh,
                                                  const f16x8* __restrict__ hfl,
                                                  const float* __restrict__ lb,
                                                  uint32_t k1t, uint32_t k2t,
                                                  float4* __restrict__ pf4,
                                                  int* __restrict__ pidx) {
  const int wv = threadIdx.x >> 6;
  const int vt = blockIdx.x * 4 + wv;
  const int lane = threadIdx.x & 63;
  __shared__ float red[4][64][5];
  const f32x4 zero = {0.f, 0.f, 0.f, 0.f};
  f32x4 aH[4]  = {zero, zero, zero, zero};
  f32x4 aM1[4] = {zero, zero, zero, zero};
  f32x4 aM2[4] = {zero, zero, zero, zero};
  const size_t wbase = (size_t)vt * 16 * 64 + lane;
  // 2-deep A-stream ring (static-indexed via full unroll; +8 VGPR vs r7's 1-deep)
  f16x8 whR[2], wlR[2];
  whR[0] = Wh[wbase];      wlR[0] = Wl[wbase];
  whR[1] = Wh[wbase + 64]; wlR[1] = Wl[wbase + 64];
  #pragma unroll
  for (int c = 0; c < 16; ++c) {
    const f16x8 whC = whR[c & 1], wlC = wlR[c & 1];
    if (c + 2 < 16) { whR[c & 1] = Wh[wbase + (c + 2) * 64]; wlR[c & 1] = Wl[wbase + (c + 2) * 64]; }
    #pragma unroll
    for (int nb = 0; nb < 4; ++nb) {
      const f16x8 bh = hfh[(c * 4 + nb) * 64 + lane];
      const f16x8 bl = hfl[(c * 4 + nb) * 64 + lane];
      aH[nb]  = __builtin_amdgcn_mfma_f32_16x16x32_f16(whC, bh, aH[nb], 0, 0, 0);
      aM1[nb] = __builtin_amdgcn_mfma_f32_16x16x32_f16(whC, bl, aM1[nb], 0, 0, 0);
      aM2[nb] = __builtin_amdgcn_mfma_f32_16x16x32_f16(wlC, bh, aM2[nb], 0, 0, 0);
    }
  }
  // epilogue: lane holds C rows v = vt*16 + (lane>>4)*4 + reg, cols b = nb*16 + (lane&15)
  const int v0 = vt * 16 + ((lane >> 4) << 2);
  const float4 bias = *(const float4*)(lb + v0);
  const float bb4[4] = {bias.x, bias.y, bias.z, bias.w};
  Part P[4];
  #pragma unroll
  for (int nb = 0; nb < 4; ++nb) {
    const int b = nb * 16 + (lane & 15);
    float lg = aH[nb][0] + (aM1[nb][0] + aM2[nb][0]) * INV2048 + bb4[0];
    Part p;
    p.bv = lg + gumbel_for(k1t, k2t, (uint32_t)(b * VV + v0));
    p.bix = v0; p.blog = lg; p.m = lg; p.s = 1.0f;
    #pragma unroll
    for (int reg = 1; reg < 4; ++reg) {
      float lg2 = aH[nb][reg] + (aM1[nb][reg] + aM2[nb][reg]) * INV2048 + bb4[reg];
      float pe = lg2 + gumbel_for(k1t, k2t, (uint32_t)(b * VV + v0 + reg));
      if (pe > p.bv) { p.bv = pe; p.bix = v0 + reg; p.blog = lg2; }
      if (lg2 > p.m) { p.s = p.s * expf(p.m - lg2) + 1.f; p.m = lg2; }
      else           { p.s += expf(lg2 - p.m); }
    }
    P[nb] = p;
  }
  #pragma unroll
  for (int msk = 16; msk <= 32; msk <<= 1) {
    #pragma unroll
    for (int nb = 0; nb < 4; ++nb) {
      Part Q;
      Q.bv   = __shfl_xor(P[nb].bv, msk, 64);
      Q.bix  = __shfl_xor(P[nb].bix, msk, 64);
      Q.blog = __shfl_xor(P[nb].blog, msk, 64);
      Q.m    = __shfl_xor(P[nb].m, msk, 64);
      Q.s    = __shfl_xor(P[nb].s, msk, 64);
      part_combine(P[nb], Q);
    }
  }
  if (lane < 16) {
    #pragma unroll
    for (int nb = 0; nb < 4; ++nb) {
      const int b = nb * 16 + lane;
      red[wv][b][0] = P[nb].bv; red[wv][b][1] = __int_as_float(P[nb].bix);
      red[wv][b][2] = P[nb].blog; red[wv][b][3] = P[nb].m; red[wv][b][4] = P[nb].s;
    }
  }
  __syncthreads();
  if (threadIdx.x < 64) {
    const int b = threadIdx.x;
    Part Pc;
    Pc.bv = red[0][b][0]; Pc.bix = __float_as_int(red[0][b][1]); Pc.blog = red[0][b][2];
    Pc.m = red[0][b][3]; Pc.s = red[0][b][4];
    #pragma unroll
    for (int w = 1; w < 4; ++w) {
      Part Q;
      Q.bv = red[w][b][0]; Q.bix = __float_as_int(red[w][b][1]); Q.blog = red[w][b][2];
      Q.m = red[w][b][3]; Q.s = red[w][b][4];
      part_combine(Pc, Q);
    }
    pf4[(size_t)blockIdx.x * BB + b] = make_float4(Pc.bv, Pc.blog, Pc.m, Pc.s);
    pidx[blockIdx.x * BB + b] = Pc.bix;
  }
}

// ---------------- k_sample2: combine nvt partials, sample, record, embed-gather ----------------
__global__ __launch_bounds__(256) void k_sample2(const float4* __restrict__ pf4,
                                                 const int* __restrict__ pidx,
                                                 const float* __restrict__ embW,
                                                 int* __restrict__ done,
                                                 float* __restrict__ x,
                                                 float* __restrict__ out,
                                                 int step, int nvt) {
  const int b = blockIdx.x;
  const int tx = threadIdx.x;
  __shared__ float red[256 * 5];
  __shared__ int stok;
  Part p; p.bv = -FLT_MAX; p.bix = 0x7fffffff; p.blog = 0.f; p.m = -FLT_MAX; p.s = 0.f;
  for (int vt = tx; vt < nvt; vt += 256) {
    float4 q = pf4[(size_t)vt * BB + b];
    Part Q; Q.bv = q.x; Q.blog = q.y; Q.m = q.z; Q.s = q.w; Q.bix = pidx[vt * BB + b];
    part_combine(p, Q);
  }
  red[tx * 5 + 0] = p.bv; red[tx * 5 + 1] = __int_as_float(p.bix); red[tx * 5 + 2] = p.blog;
  red[tx * 5 + 3] = p.m;  red[tx * 5 + 4] = p.s;
  __syncthreads();
  for (int st = 128; st > 0; st >>= 1) {
    if (tx < st) {
      const int s0 = tx * 5, s1 = (tx + st) * 5;
      Part P, Q;
      P.bv = red[s0]; P.bix = __float_as_int(red[s0 + 1]); P.blog = red[s0 + 2]; P.m = red[s0 + 3]; P.s = red[s0 + 4];
      Q.bv = red[s1]; Q.bix = __float_as_int(red[s1 + 1]); Q.blog = red[s1 + 2]; Q.m = red[s1 + 3]; Q.s = red[s1 + 4];
      part_combine(P, Q);
      red[s0] = P.bv; red[s0 + 1] = __int_as_float(P.bix); red[s0 + 2] = P.blog; red[s0 + 3] = P.m; red[s0 + 4] = P.s;
    }
    __syncthreads();
  }
  if (tx == 0) {
    const int tok = __float_as_int(red[1]);
    const float blog = red[2], M = red[3], S = red[4];
    const float lp = blog - (M + logf(S));
    const int dn = done[b];
    out[b * TT + step] = dn ? 0.0f : (float)tok;
    out[BB * TT + b * TT + step] = dn ? 0.0f : lp;
    done[b] = dn | (tok == 2);
    stok = tok;
  }
  __syncthreads();
  const int tok = stok;
  for (int e = tx; e < EE; e += 256) x[b * EE + e] = embW[(size_t)tok * EE + e];
}

// ============================================================================
// mid-path fallback (r5 proven) — only used if ws_size < 73 MB (never seen)
// ============================================================================
__global__ __launch_bounds__(256) void k_lstm_update(const float* __restrict__ gatesP,
                                                     const float* __restrict__ b_ih,
                                                     const float* __restrict__ b_hh,
                                                     float* __restrict__ cT,
                                                     float* __restrict__ hT) {
  const int blk = blockIdx.x;
  const int tx = threadIdx.x;
  const int b = tx & 63;
  const int dk = tx >> 6;
  #pragma unroll
  for (int r = 0; r < 2; ++r) {
    const int k = blk * 8 + dk + r * 4;
    float g[4];
    #pragma unroll
    for (int gi = 0; gi < 4; ++gi) {
      const int j = gi * 512 + k;
      float s = 0.f;
      #pragma unroll
      for (int kc = 0; kc < 8; ++kc) s += gatesP[((size_t)kc * 2048 + j) * BB + b];
      g[gi] = s + b_ih[j] + b_hh[j];
    }
    const float ig = 1.f / (1.f + expf(-g[0]));
    const float fg = 1.f / (1.f + expf(-g[1]));
    const float gg = tanhf(g[2]);
    const float og = 1.f / (1.f + expf(-g[3]));
    const float c = fg * cT[k * BB + b] + ig * gg;
    cT[k * BB + b] = c;
    hT[k * BB + b] = og * tanhf(c);
  }
}

__global__ __launch_bounds__(128) void k_logits2(const float* __restrict__ hT,
                                                 const float* __restrict__ LW,
                                                 const float* __restrict__ lb,
                                                 uint32_t k1t, uint32_t k2t,
                                                 float4* __restrict__ pf4,
                                                 int* __restrict__ pidx) {
  const int vt = blockIdx.x;
  const int tx = threadIdx.x;
  __shared__ float lds[5120];
  float* wTs = lds;
  const int vthr = tx & 15;
  const int bthr = tx >> 4;
  const int vi = vthr * 2;
  const int bi = bthr * 8;
  const int vq = tx >> 4;
  const int ks = tx & 15;
  float acc[2][8] = {};
  for (int kt = 0; kt < 8; ++kt) {
    const int kg = kt * 64;
    #pragma unroll
    for (int s = 0; s < 4; ++s) {
      const int kk = ks + 16 * s;
      const size_t rb = (size_t)(vt * 32 + 4 * vq) * HH + kg + kk;
      float w0 = LW[rb];
      float w1 = LW[rb + HH];
      float w2 = LW[rb + 2 * HH];
      float w3 = LW[rb + 3 * HH];
      const int ph = (4 * vq) ^ (4 * (kk & 7));
      *(float4*)&wTs[kk * 32 + ph] = make_float4(w0, w1, w2, w3);
    }
    __syncthreads();
    #pragma unroll 4
    for (int kk = 0; kk < 64; ++kk) {
      const float* hrow = hT + (size_t)(kg + kk) * BB;
      const float4 h0 = *(const float4*)(hrow + bi);
      const float4 h1 = *(const float4*)(hrow + bi + 4);
      const float2 wv = *(const float2*)&wTs[kk * 32 + (vi ^ (4 * (kk & 7)))];
      acc[0][0] = fmaf(wv.x, h0.x, acc[0][0]); acc[0][1] = fmaf(wv.x, h0.y, acc[0][1]);
      acc[0][2] = fmaf(wv.x, h0.z, acc[0][2]); acc[0][3] = fmaf(wv.x, h0.w, acc[0][3]);
      acc[0][4] = fmaf(wv.x, h1.x, acc[0][4]); acc[0][5] = fmaf(wv.x, h1.y, acc[0][5]);
      acc[0][6] = fmaf(wv.x, h1.z, acc[0][6]); acc[0][7] = fmaf(wv.x, h1.w, acc[0][7]);
      acc[1][0] = fmaf(wv.y, h0.x, acc[1][0]); acc[1][1] = fmaf(wv.y, h0.y, acc[1][1]);
      acc[1][2] = fmaf(wv.y, h0.z, acc[1][2]); acc[1][3] = fmaf(wv.y, h0.w, acc[1][3]);
      acc[1][4] = fmaf(wv.y, h1.x, acc[1][4]); acc[1][5] = fmaf(wv.y, h1.y, acc[1][5]);
      acc[1][6] = fmaf(wv.y, h1.z, acc[1][6]); acc[1][7] = fmaf(wv.y, h1.w, acc[1][7]);
    }
    __syncthreads();
  }
  const int v0g = vt * 32 + vi;
  const float bias0 = lb[v0g];
  const float bias1 = lb[v0g + 1];
  float* red = lds;
  #pragma unroll
  for (int bb = 0; bb < 8; ++bb) {
    const int b = bi + bb;
    const float lg0 = acc[0][bb] + bias0;
    const float lg1 = acc[1][bb] + bias1;
    Part p;
    p.bv = lg0 + gumbel_for(k1t, k2t, (uint32_t)(b * VV + v0g));
    p.bix = v0g; p.blog = lg0;
    const float pe1 = lg1 + gumbel_for(k1t, k2t, (uint32_t)(b * VV + v0g + 1));
    if (pe1 > p.bv) { p.bv = pe1; p.bix = v0g + 1; p.blog = lg1; }
    if (lg0 >= lg1) { p.m = lg0; p.s = 1.f + expf(lg1 - lg0); }
    else            { p.m = lg1; p.s = 1.f + expf(lg0 - lg1); }
    const int slot = (b * 16 + vthr) * 5;
    red[slot + 0] = p.bv; red[slot + 1] = __int_as_float(p.bix); red[slot + 2] = p.blog;
    red[slot + 3] = p.m;  red[slot + 4] = p.s;
  }
  __syncthreads();
  if (tx < 64) {
    const int b = tx;
    Part P;
    { const int s0 = (b * 16) * 5;
      P.bv = red[s0]; P.bix = __float_as_int(red[s0 + 1]); P.blog = red[s0 + 2];
      P.m = red[s0 + 3]; P.s = red[s0 + 4]; }
    #pragma unroll
    for (int c = 1; c < 16; ++c) {
      const int s0 = (b * 16 + c) * 5;
      Part Q; Q.bv = red[s0]; Q.bix = __float_as_int(red[s0 + 1]); Q.blog = red[s0 + 2];
      Q.m = red[s0 + 3]; Q.s = red[s0 + 4];
      part_combine(P, Q);
    }
    pf4[(size_t)vt * BB + b] = make_float4(P.bv, P.blog, P.m, P.s);
    pidx[vt * BB + b] = P.bix;
  }
}

// ---------------- launch ----------------
extern "C" void kernel_launch(void* const* d_in, const int* in_sizes, int n_in,
                              void* d_out, int out_size, void* d_ws, size_t ws_size,
                              hipStream_t stream) {
  const float* features = (const float*)d_in[0];
  const float* embW     = (const float*)d_in[4];
  const float* Wih      = (const float*)d_in[5];
  const float* Whh      = (const float*)d_in[6];
  const float* bih      = (const float*)d_in[7];
  const float* bhh      = (const float*)d_in[8];
  const float* LW       = (const float*)d_in[9];
  const float* lb       = (const float*)d_in[10];
  float* out = (float*)d_out;

  uint32_t keys[TT][2];
  for (int t = 0; t < TT; ++t) tf2x32(0u, 42u, 0u, (uint32_t)t, keys[t][0], keys[t][1]);

  float* ws = (float*)d_ws;

  if (ws_size >= (size_t)73000000) {
    // ---------------- fast path: r7 structure verbatim + 2-deep A-prefetch in logits ----------------
    float* hA = ws;                                     // 32768
    float* hB = ws + 32768;
    float* cT = ws + 65536;
    float* x  = ws + 98304;
    float*  gatesP = ws + 131072;                       // 1,048,576 f
    float4* pf4    = (float4*)(ws + 1179648);
    int*    pidx   = (int*)(ws + 1691648);
    int*    done   = (int*)(ws + 1819648);
    _Float16* hfh  = (_Float16*)(ws + 1819712);
    _Float16* hfl  = (_Float16*)(ws + 1836096);
    _Float16* Whi  = (_Float16*)(ws + 1852480);
    _Float16* Wlo  = (_Float16*)(ws + 10044480);

    k_convW2<<<dim3(500, 8), dim3(256), 0, stream>>>(LW, Whi, Wlo);
    k_init<<<dim3(128), dim3(256), 0, stream>>>(hA, cT, done);
    const float* hin = hA;
    float* hout = hB;
    for (int t = 0; t < TT; ++t) {
      const float* xin = (t == 0) ? features : x;
      k_gates<<<dim3(32, 8), dim3(256), 0, stream>>>(xin, hin, Wih, Whh, gatesP);
      k_lstm_update_frag<<<dim3(64), dim3(256), 0, stream>>>(gatesP, bih, bhh, cT, hout, hfh, hfl);
      k_logits4b<<<dim3(500), dim3(256), 0, stream>>>((const f16x8*)Whi, (const f16x8*)Wlo,
                                                      (const f16x8*)hfh, (const f16x8*)hfl,
                                                      lb, keys[t][0], keys[t][1], pf4, pidx);
      k_sample2<<<dim3(64), dim3(256), 0, stream>>>(pf4, pidx, embW, done, x, out, t, 500);
      const float* tmp = hout; hout = (float*)hin; hin = tmp;
    }
  } else {
    // ---------------- mid path (r5 proven, ~6.4 MB) ----------------
    float* hA = ws;
    float* hB = ws + 32768;
    float* cT = ws + 65536;
    float* x  = ws + 98304;
    float*  gatesP = ws + 131072;
    float4* pf4    = (float4*)(ws + 131072 + 1048576);
    int*    pidx   = (int*)(ws + 131072 + 1048576 + 256000);
    int*    done   = (int*)(ws + 131072 + 1048576 + 256000 + 64000);

    k_init<<<dim3(128), dim3(256), 0, stream>>>(hA, cT, done);
    const float* hin = hA;
    float* hout = hB;
    for (int t = 0; t < TT; ++t) {
      const float* xin = (t == 0) ? features : x;
      k_gates<<<dim3(32, 8), dim3(256), 0, stream>>>(xin, hin, Wih, Whh, gatesP);
      k_lstm_update<<<dim3(64), dim3(256), 0, stream>>>(gatesP, bih, bhh, cT, hout);
      k_logits2<<<dim3(1000), dim3(128), 0, stream>>>(hout, LW, lb, keys[t][0], keys[t][1], pf4, pidx);
      k_sample2<<<dim3(64), dim3(256), 0, stream>>>(pf4, pidx, embW, done, x, out, t, 1000);
      const float* tmp = hout; hout = (float*)hin; hin = tmp;
    }
  }
}

// Round 11
// 930.193 us; speedup vs baseline: 1.3161x; 1.1037x over previous
//
#include <hip/hip_runtime.h>
#include <hip/hip_bf16.h>
#include <stdint.h>
#include <float.h>

// B=64, E=H=512, V=32000, T=20 (lengths[0]=T so max(lengths)==20 always)
#define BB 64
#define EE 512
#define HH 512
#define VV 32000
#define TT 20
#define INV2048 0.00048828125f

typedef _Float16 f16x8 __attribute__((ext_vector_type(8)));
typedef float f32x4 __attribute__((ext_vector_type(4)));

// ---------------- threefry2x32 (JAX-exact, 20 rounds) ----------------
__device__ __host__ __forceinline__ void tf2x32(uint32_t k0, uint32_t k1, uint32_t x0, uint32_t x1,
                                                uint32_t& o0, uint32_t& o1) {
  const uint32_t k2 = k0 ^ k1 ^ 0x1BD11BDAu;
  x0 += k0; x1 += k1;
#define RND(R) { x0 += x1; x1 = (x1 << R) | (x1 >> (32 - R)); x1 ^= x0; }
  RND(13) RND(15) RND(26) RND(6)
  x0 += k1; x1 += k2 + 1u;
  RND(17) RND(29) RND(16) RND(24)
  x0 += k2; x1 += k0 + 2u;
  RND(13) RND(15) RND(26) RND(6)
  x0 += k0; x1 += k1 + 3u;
  RND(17) RND(29) RND(16) RND(24)
  x0 += k1; x1 += k2 + 4u;
  RND(13) RND(15) RND(26) RND(6)
  x0 += k2; x1 += k0 + 5u;
#undef RND
  o0 = x0; o1 = x1;
}

// partitionable-threefry (JAX >= 0.5 default): bits = o0^o1 of tf(key,(0,idx));
// uniform = bitcast(0x3f800000|bits>>9)-1, 0 -> tiny; gumbel = -log(-log(u))
__device__ __forceinline__ float gumbel_for(uint32_t k1t, uint32_t k2t, uint32_t idx) {
  uint32_t o0, o1; tf2x32(k1t, k2t, 0u, idx, o0, o1);
  uint32_t bits = o0 ^ o1;
  uint32_t mant = bits >> 9;
  float f = __uint_as_float(0x3f800000u | mant) - 1.0f;
  float u = mant ? f : 1.1754943508222875e-38f;
  return -logf(-logf(u));
}

struct Part { float bv; int bix; float blog; float m; float s; };

__device__ __forceinline__ void part_combine(Part& P, const Part& Q) {
  if (Q.bv > P.bv || (Q.bv == P.bv && Q.bix < P.bix)) { P.bv = Q.bv; P.bix = Q.bix; P.blog = Q.blog; }
  if (Q.m > P.m) { P.s = P.s * expf(P.m - Q.m) + Q.s; P.m = Q.m; }
  else           { P.s += Q.s * expf(Q.m - P.m); }
}

// ---------------- K0: init ----------------
__global__ __launch_bounds__(256) void k_init(float* __restrict__ hA, float* __restrict__ cT,
                                              int* __restrict__ done) {
  int i = blockIdx.x * 256 + threadIdx.x;
  if (i < HH * BB) { hA[i] = 0.f; cT[i] = 0.f; }
  if (i < BB) done[i] = 0;
}

// ---------------- k_gates: split-k gates GEMM (proven) ----------------
__global__ __launch_bounds__(256) void k_gates(const float* __restrict__ xin,  // [64][512] b-major
                                               const float* __restrict__ hT,   // [512][64]
                                               const float* __restrict__ Wih,
                                               const float* __restrict__ Whh,
                                               float* __restrict__ gatesP) {
  const int jt = blockIdx.x;   // 0..31
  const int kc = blockIdx.y;   // 0..7
  const int tx = threadIdx.x;
  __shared__ float a[64][64];
  __shared__ float wj[64][68];
  const int bi = (tx & 15) * 4;
  const int ji = (tx >> 4) * 4;
  float acc[4][4] = {};
  const float* Wsrc = (kc < 4) ? Wih : Whh;
  for (int s = 0; s < 2; ++s) {
    const int kg = kc * 128 + s * 64;
    if (kc < 4) {
      #pragma unroll
      for (int r = 0; r < 4; ++r) {
        int fi = r * 256 + tx;
        int b = fi >> 4, k4 = (fi & 15) * 4;
        const float4 v = *(const float4*)(xin + b * EE + kg + k4);
        a[k4 + 0][b] = v.x; a[k4 + 1][b] = v.y; a[k4 + 2][b] = v.z; a[k4 + 3][b] = v.w;
      }
    } else {
      #pragma unroll
      for (int r = 0; r < 4; ++r) {
        int fi = r * 256 + tx;
        int row = fi >> 4, c4 = (fi & 15) * 4;
        *(float4*)(&a[row][c4]) = *(const float4*)(hT + (kg - 512 + row) * BB + c4);
      }
    }
    const int kcol = kg & 511;
    #pragma unroll
    for (int r = 0; r < 4; ++r) {
      int fi = r * 256 + tx;
      int j = fi >> 4, k4 = (fi & 15) * 4;
      const float4 v = *(const float4*)(Wsrc + (size_t)(jt * 64 + j) * EE + kcol + k4);
      wj[k4 + 0][j] = v.x; wj[k4 + 1][j] = v.y; wj[k4 + 2][j] = v.z; wj[k4 + 3][j] = v.w;
    }
    __syncthreads();
    #pragma unroll 8
    for (int kk = 0; kk < 64; ++kk) {
      const float4 av = *(const float4*)(&a[kk][bi]);
      const float4 wv = *(const float4*)(&wj[kk][ji]);
      const float avx[4] = {av.x, av.y, av.z, av.w};
      const float wvx[4] = {wv.x, wv.y, wv.z, wv.w};
      #pragma unroll
      for (int jj = 0; jj < 4; ++jj)
        #pragma unroll
        for (int bb = 0; bb < 4; ++bb)
          acc[jj][bb] = fmaf(wvx[jj], avx[bb], acc[jj][bb]);
    }
    __syncthreads();
  }
  #pragma unroll
  for (int jj = 0; jj < 4; ++jj) {
    float4 o = make_float4(acc[jj][0], acc[jj][1], acc[jj][2], acc[jj][3]);
    *(float4*)(gatesP + ((size_t)kc * 2048 + jt * 64 + ji + jj) * BB + bi) = o;
  }
}

// ---------------- k_lstm_update (mid path) ----------------
__global__ __launch_bounds__(256) void k_lstm_update(const float* __restrict__ gatesP,
                                                     const float* __restrict__ b_ih,
                                                     const float* __restrict__ b_hh,
                                                     float* __restrict__ cT,
                                                     float* __restrict__ hT) {
  const int blk = blockIdx.x;
  const int tx = threadIdx.x;
  const int b = tx & 63;
  const int dk = tx >> 6;
  #pragma unroll
  for (int r = 0; r < 2; ++r) {
    const int k = blk * 8 + dk + r * 4;
    float g[4];
    #pragma unroll
    for (int gi = 0; gi < 4; ++gi) {
      const int j = gi * 512 + k;
      float s = 0.f;
      #pragma unroll
      for (int kc = 0; kc < 8; ++kc) s += gatesP[((size_t)kc * 2048 + j) * BB + b];
      g[gi] = s + b_ih[j] + b_hh[j];
    }
    const float ig = 1.f / (1.f + expf(-g[0]));
    const float fg = 1.f / (1.f + expf(-g[1]));
    const float gg = tanhf(g[2]);
    const float og = 1.f / (1.f + expf(-g[3]));
    const float c = fg * cT[k * BB + b] + ig * gg;
    cT[k * BB + b] = c;
    hT[k * BB + b] = og * tanhf(c);
  }
}

// ---------------- k_lstm_update_frag: + fp16 hi/lo B-fragment writes ----------------
// B-frag layout: n=lane&15 (b%16), k = c*32 + (lane>>4)*8 + j; idx = ((c*4+nb)*64+lane)*8+j
__global__ __launch_bounds__(256) void k_lstm_update_frag(const float* __restrict__ gatesP,
                                                          const float* __restrict__ b_ih,
                                                          const float* __restrict__ b_hh,
                                                          float* __restrict__ cT,
                                                          float* __restrict__ hT,
                                                          _Float16* __restrict__ hfh,
                                                          _Float16* __restrict__ hfl) {
  const int blk = blockIdx.x;
  const int tx = threadIdx.x;
  const int b = tx & 63;
  const int dk = tx >> 6;
  #pragma unroll
  for (int r = 0; r < 2; ++r) {
    const int k = blk * 8 + dk + r * 4;
    float g[4];
    #pragma unroll
    for (int gi = 0; gi < 4; ++gi) {
      const int j = gi * 512 + k;
      float s = 0.f;
      #pragma unroll
      for (int kc = 0; kc < 8; ++kc) s += gatesP[((size_t)kc * 2048 + j) * BB + b];
      g[gi] = s + b_ih[j] + b_hh[j];
    }
    const float ig = 1.f / (1.f + expf(-g[0]));
    const float fg = 1.f / (1.f + expf(-g[1]));
    const float gg = tanhf(g[2]);
    const float og = 1.f / (1.f + expf(-g[3]));
    const float c = fg * cT[k * BB + b] + ig * gg;
    cT[k * BB + b] = c;
    const float h = og * tanhf(c);
    hT[k * BB + b] = h;
    const _Float16 hh = (_Float16)h;
    const _Float16 hl = (_Float16)((h - (float)hh) * 2048.0f);
    const int cc = k >> 5, kr = k & 31;
    const int lane = (kr >> 3) * 16 + (b & 15), j = kr & 7, nb = b >> 4;
    const int idx = ((cc * 4 + nb) * 64 + lane) * 8 + j;
    hfh[idx] = hh; hfl[idx] = hl;
  }
}

// ---------------- k_convW2: LDS-transposed, fully coalesced f32 W -> fp16 hi/lo frags ----------------
// grid (500, 8): block (bv, bk) handles v in [bv*64, bv*64+64), k in [bk*64, bk*64+64)
__global__ __launch_bounds__(256) void k_convW2(const float* __restrict__ LW,
                                                _Float16* __restrict__ Wh,
                                                _Float16* __restrict__ Wl) {
  const int bv = blockIdx.x, bk = blockIdx.y;
  const int tx = threadIdx.x;
  __shared__ float lds[64][65];
  // coalesced read 64x64 f32 tile
  #pragma unroll
  for (int r = 0; r < 4; ++r) {
    const int fi = r * 256 + tx;
    const int vl = fi >> 4, k4 = (fi & 15) * 4;
    const float4 v = *(const float4*)(LW + (size_t)(bv * 64 + vl) * HH + bk * 64 + k4);
    lds[vl][k4] = v.x; lds[vl][k4 + 1] = v.y; lds[vl][k4 + 2] = v.z; lds[vl][k4 + 3] = v.w;
  }
  __syncthreads();
  // coalesced frag-layout write: 8 frags (vbl 0..3, cl 0..1) x 64 lanes x f16x8
  #pragma unroll
  for (int r = 0; r < 2; ++r) {
    const int u = r * 256 + tx;           // 0..511
    const int frag = u >> 6;              // 0..7
    const int vbl = frag >> 1, cl = frag & 1;
    const int lane = u & 63;
    const int m = lane & 15, lh = lane >> 4;
    f16x8 hi, lo;
    #pragma unroll
    for (int j = 0; j < 8; ++j) {
      const float f = lds[vbl * 16 + m][cl * 32 + lh * 8 + j];
      const _Float16 h = (_Float16)f;
      hi[j] = h;
      lo[j] = (_Float16)((f - (float)h) * 2048.0f);
    }
    const size_t o = (((size_t)(bv * 4 + vbl) * 16 + (bk * 2 + cl)) * 64 + lane) * 8;
    *(f16x8*)(Wh + o) = hi;
    *(f16x8*)(Wl + o) = lo;
  }
}

// ---------------- k_logits4: 500 blocks x 4 waves; prefetched W, split-acc MFMA ----------------
// Wave w of block handles v-tile vt = bid*4 + w (16 v), all 64 b, full K=512.
__global__ __launch_bounds__(256) void k_logits4(const f16x8* __restrict__ Wh,
                                                 const f16x8* __restrict__ Wl,
                                                 const f16x8* __restrict__ hfh,
                                                 const f16x8* __restrict__ hfl,
                                                 const float* __restrict__ lb,
                                                 uint32_t k1t, uint32_t k2t,
                                                 float4* __restrict__ pf4,
                                                 int* __restrict__ pidx) {
  const int wv = threadIdx.x >> 6;
  const int vt = blockIdx.x * 4 + wv;     // 0..1999
  const int lane = threadIdx.x & 63;
  __shared__ float red[4][64][5];
  const f32x4 zero = {0.f, 0.f, 0.f, 0.f};
  f32x4 aH[4]  = {zero, zero, zero, zero};
  f32x4 aM1[4] = {zero, zero, zero, zero};
  f32x4 aM2[4] = {zero, zero, zero, zero};
  const size_t wbase = (size_t)vt * 16 * 64 + lane;
  f16x8 whC = Wh[wbase], wlC = Wl[wbase];
  #pragma unroll 4
  for (int c = 0; c < 16; ++c) {
    f16x8 whN, wlN;
    if (c < 15) { whN = Wh[wbase + (c + 1) * 64]; wlN = Wl[wbase + (c + 1) * 64]; }
    #pragma unroll
    for (int nb = 0; nb < 4; ++nb) {
      const f16x8 bh = hfh[(c * 4 + nb) * 64 + lane];
      const f16x8 bl = hfl[(c * 4 + nb) * 64 + lane];
      aH[nb]  = __builtin_amdgcn_mfma_f32_16x16x32_f16(whC, bh, aH[nb], 0, 0, 0);
      aM1[nb] = __builtin_amdgcn_mfma_f32_16x16x32_f16(whC, bl, aM1[nb], 0, 0, 0);
      aM2[nb] = __builtin_amdgcn_mfma_f32_16x16x32_f16(wlC, bh, aM2[nb], 0, 0, 0);
    }
    whC = whN; wlC = wlN;
  }
  // epilogue: lane holds C rows v = vt*16 + (lane>>4)*4 + reg, cols b = nb*16 + (lane&15)
  const int v0 = vt * 16 + ((lane >> 4) << 2);
  const float4 bias = *(const float4*)(lb + v0);
  const float bb4[4] = {bias.x, bias.y, bias.z, bias.w};
  Part P[4];
  #pragma unroll
  for (int nb = 0; nb < 4; ++nb) {
    const int b = nb * 16 + (lane & 15);
    float lg = aH[nb][0] + (aM1[nb][0] + aM2[nb][0]) * INV2048 + bb4[0];
    Part p;
    p.bv = lg + gumbel_for(k1t, k2t, (uint32_t)(b * VV + v0));
    p.bix = v0; p.blog = lg; p.m = lg; p.s = 1.0f;
    #pragma unroll
    for (int reg = 1; reg < 4; ++reg) {
      float lg2 = aH[nb][reg] + (aM1[nb][reg] + aM2[nb][reg]) * INV2048 + bb4[reg];
      float pe = lg2 + gumbel_for(k1t, k2t, (uint32_t)(b * VV + v0 + reg));
      if (pe > p.bv) { p.bv = pe; p.bix = v0 + reg; p.blog = lg2; }
      if (lg2 > p.m) { p.s = p.s * expf(p.m - lg2) + 1.f; p.m = lg2; }
      else           { p.s += expf(lg2 - p.m); }
    }
    P[nb] = p;
  }
  #pragma unroll
  for (int msk = 16; msk <= 32; msk <<= 1) {
    #pragma unroll
    for (int nb = 0; nb < 4; ++nb) {
      Part Q;
      Q.bv   = __shfl_xor(P[nb].bv, msk, 64);
      Q.bix  = __shfl_xor(P[nb].bix, msk, 64);
      Q.blog = __shfl_xor(P[nb].blog, msk, 64);
      Q.m    = __shfl_xor(P[nb].m, msk, 64);
      Q.s    = __shfl_xor(P[nb].s, msk, 64);
      part_combine(P[nb], Q);
    }
  }
  if (lane < 16) {
    #pragma unroll
    for (int nb = 0; nb < 4; ++nb) {
      const int b = nb * 16 + lane;
      red[wv][b][0] = P[nb].bv; red[wv][b][1] = __int_as_float(P[nb].bix);
      red[wv][b][2] = P[nb].blog; red[wv][b][3] = P[nb].m; red[wv][b][4] = P[nb].s;
    }
  }
  __syncthreads();
  // combine the block's 4 v-tiles (ascending v keeps first-lowest tie semantics)
  if (threadIdx.x < 64) {
    const int b = threadIdx.x;
    Part Pc;
    Pc.bv = red[0][b][0]; Pc.bix = __float_as_int(red[0][b][1]); Pc.blog = red[0][b][2];
    Pc.m = red[0][b][3]; Pc.s = red[0][b][4];
    #pragma unroll
    for (int w = 1; w < 4; ++w) {
      Part Q;
      Q.bv = red[w][b][0]; Q.bix = __float_as_int(red[w][b][1]); Q.blog = red[w][b][2];
      Q.m = red[w][b][3]; Q.s = red[w][b][4];
      part_combine(Pc, Q);
    }
    pf4[(size_t)blockIdx.x * BB + b] = make_float4(Pc.bv, Pc.blog, Pc.m, Pc.s);
    pidx[blockIdx.x * BB + b] = Pc.bix;
  }
}

// ---------------- k_logits2 (mid path, r5 proven) ----------------
__global__ __launch_bounds__(128) void k_logits2(const float* __restrict__ hT,
                                                 const float* __restrict__ LW,
                                                 const float* __restrict__ lb,
                                                 uint32_t k1t, uint32_t k2t,
                                                 float4* __restrict__ pf4,
                                                 int* __restrict__ pidx) {
  const int vt = blockIdx.x;
  const int tx = threadIdx.x;
  __shared__ float lds[5120];
  float* wTs = lds;
  const int vthr = tx & 15;
  const int bthr = tx >> 4;
  const int vi = vthr * 2;
  const int bi = bthr * 8;
  const int vq = tx >> 4;
  const int ks = tx & 15;
  float acc[2][8] = {};
  for (int kt = 0; kt < 8; ++kt) {
    const int kg = kt * 64;
    #pragma unroll
    for (int s = 0; s < 4; ++s) {
      const int kk = ks + 16 * s;
      const size_t rb = (size_t)(vt * 32 + 4 * vq) * HH + kg + kk;
      float w0 = LW[rb];
      float w1 = LW[rb + HH];
      float w2 = LW[rb + 2 * HH];
      float w3 = LW[rb + 3 * HH];
      const int ph = (4 * vq) ^ (4 * (kk & 7));
      *(float4*)&wTs[kk * 32 + ph] = make_float4(w0, w1, w2, w3);
    }
    __syncthreads();
    #pragma unroll 4
    for (int kk = 0; kk < 64; ++kk) {
      const float* hrow = hT + (size_t)(kg + kk) * BB;
      const float4 h0 = *(const float4*)(hrow + bi);
      const float4 h1 = *(const float4*)(hrow + bi + 4);
      const float2 wv = *(const float2*)&wTs[kk * 32 + (vi ^ (4 * (kk & 7)))];
      acc[0][0] = fmaf(wv.x, h0.x, acc[0][0]); acc[0][1] = fmaf(wv.x, h0.y, acc[0][1]);
      acc[0][2] = fmaf(wv.x, h0.z, acc[0][2]); acc[0][3] = fmaf(wv.x, h0.w, acc[0][3]);
      acc[0][4] = fmaf(wv.x, h1.x, acc[0][4]); acc[0][5] = fmaf(wv.x, h1.y, acc[0][5]);
      acc[0][6] = fmaf(wv.x, h1.z, acc[0][6]); acc[0][7] = fmaf(wv.x, h1.w, acc[0][7]);
      acc[1][0] = fmaf(wv.y, h0.x, acc[1][0]); acc[1][1] = fmaf(wv.y, h0.y, acc[1][1]);
      acc[1][2] = fmaf(wv.y, h0.z, acc[1][2]); acc[1][3] = fmaf(wv.y, h0.w, acc[1][3]);
      acc[1][4] = fmaf(wv.y, h1.x, acc[1][4]); acc[1][5] = fmaf(wv.y, h1.y, acc[1][5]);
      acc[1][6] = fmaf(wv.y, h1.z, acc[1][6]); acc[1][7] = fmaf(wv.y, h1.w, acc[1][7]);
    }
    __syncthreads();
  }
  const int v0g = vt * 32 + vi;
  const float bias0 = lb[v0g];
  const float bias1 = lb[v0g + 1];
  float* red = lds;
  #pragma unroll
  for (int bb = 0; bb < 8; ++bb) {
    const int b = bi + bb;
    const float lg0 = acc[0][bb] + bias0;
    const float lg1 = acc[1][bb] + bias1;
    Part p;
    p.bv = lg0 + gumbel_for(k1t, k2t, (uint32_t)(b * VV + v0g));
    p.bix = v0g; p.blog = lg0;
    const float pe1 = lg1 + gumbel_for(k1t, k2t, (uint32_t)(b * VV + v0g + 1));
    if (pe1 > p.bv) { p.bv = pe1; p.bix = v0g + 1; p.blog = lg1; }
    if (lg0 >= lg1) { p.m = lg0; p.s = 1.f + expf(lg1 - lg0); }
    else            { p.m = lg1; p.s = 1.f + expf(lg0 - lg1); }
    const int slot = (b * 16 + vthr) * 5;
    red[slot + 0] = p.bv; red[slot + 1] = __int_as_float(p.bix); red[slot + 2] = p.blog;
    red[slot + 3] = p.m;  red[slot + 4] = p.s;
  }
  __syncthreads();
  if (tx < 64) {
    const int b = tx;
    Part P;
    { const int s0 = (b * 16) * 5;
      P.bv = red[s0]; P.bix = __float_as_int(red[s0 + 1]); P.blog = red[s0 + 2];
      P.m = red[s0 + 3]; P.s = red[s0 + 4]; }
    #pragma unroll
    for (int c = 1; c < 16; ++c) {
      const int s0 = (b * 16 + c) * 5;
      Part Q; Q.bv = red[s0]; Q.bix = __float_as_int(red[s0 + 1]); Q.blog = red[s0 + 2];
      Q.m = red[s0 + 3]; Q.s = red[s0 + 4];
      part_combine(P, Q);
    }
    pf4[(size_t)vt * BB + b] = make_float4(P.bv, P.blog, P.m, P.s);
    pidx[vt * BB + b] = P.bix;
  }
}

// ---------------- k_sample2: combine nvt partials, sample, record, embed-gather ----------------
__global__ __launch_bounds__(256) void k_sample2(const float4* __restrict__ pf4,
                                                 const int* __restrict__ pidx,
                                                 const float* __restrict__ embW,
                                                 int* __restrict__ done,
                                                 float* __restrict__ x,
                                                 float* __restrict__ out,
                                                 int step, int nvt) {
  const int b = blockIdx.x;
  const int tx = threadIdx.x;
  __shared__ float red[256 * 5];
  __shared__ int stok;
  Part p; p.bv = -FLT_MAX; p.bix = 0x7fffffff; p.blog = 0.f; p.m = -FLT_MAX; p.s = 0.f;
  for (int vt = tx; vt < nvt; vt += 256) {
    float4 q = pf4[(size_t)vt * BB + b];
    Part Q; Q.bv = q.x; Q.blog = q.y; Q.m = q.z; Q.s = q.w; Q.bix = pidx[vt * BB + b];
    part_combine(p, Q);
  }
  red[tx * 5 + 0] = p.bv; red[tx * 5 + 1] = __int_as_float(p.bix); red[tx * 5 + 2] = p.blog;
  red[tx * 5 + 3] = p.m;  red[tx * 5 + 4] = p.s;
  __syncthreads();
  for (int st = 128; st > 0; st >>= 1) {
    if (tx < st) {
      const int s0 = tx * 5, s1 = (tx + st) * 5;
      Part P, Q;
      P.bv = red[s0]; P.bix = __float_as_int(red[s0 + 1]); P.blog = red[s0 + 2]; P.m = red[s0 + 3]; P.s = red[s0 + 4];
      Q.bv = red[s1]; Q.bix = __float_as_int(red[s1 + 1]); Q.blog = red[s1 + 2]; Q.m = red[s1 + 3]; Q.s = red[s1 + 4];
      part_combine(P, Q);
      red[s0] = P.bv; red[s0 + 1] = __int_as_float(P.bix); red[s0 + 2] = P.blog; red[s0 + 3] = P.m; red[s0 + 4] = P.s;
    }
    __syncthreads();
  }
  if (tx == 0) {
    const int tok = __float_as_int(red[1]);
    const float blog = red[2], M = red[3], S = red[4];
    const float lp = blog - (M + logf(S));
    const int dn = done[b];
    out[b * TT + step] = dn ? 0.0f : (float)tok;
    out[BB * TT + b * TT + step] = dn ? 0.0f : lp;
    done[b] = dn | (tok == 2);
    stok = tok;
  }
  __syncthreads();
  const int tok = stok;
  for (int e = tx; e < EE; e += 256) x[b * EE + e] = embW[(size_t)tok * EE + e];
}

// ---------------- launch ----------------
extern "C" void kernel_launch(void* const* d_in, const int* in_sizes, int n_in,
                              void* d_out, int out_size, void* d_ws, size_t ws_size,
                              hipStream_t stream) {
  const float* features = (const float*)d_in[0];
  const float* embW     = (const float*)d_in[4];
  const float* Wih      = (const float*)d_in[5];
  const float* Whh      = (const float*)d_in[6];
  const float* bih      = (const float*)d_in[7];
  const float* bhh      = (const float*)d_in[8];
  const float* LW       = (const float*)d_in[9];
  const float* lb       = (const float*)d_in[10];
  float* out = (float*)d_out;

  // step keys: partitionable (foldlike) split of key(42)
  uint32_t keys[TT][2];
  for (int t = 0; t < TT; ++t) tf2x32(0u, 42u, 0u, (uint32_t)t, keys[t][0], keys[t][1]);

  float* ws = (float*)d_ws;
  float* hA = ws;                 // 32768 f
  float* hB = ws + 32768;
  float* cT = ws + 65536;
  float* x  = ws + 98304;

  if (ws_size >= (size_t)73000000) {
    // ---------------- MFMA fast path (r7, measured 940 us) ----------------
    float*  gatesP = ws + 131072;                        // 1,048,576 f
    float4* pf4    = (float4*)(ws + 1179648);            // 500*64*4 f
    int*    pidx   = (int*)(ws + 1691648);
    int*    done   = (int*)(ws + 1819648);
    _Float16* hfh  = (_Float16*)(ws + 1819712);
    _Float16* hfl  = (_Float16*)(ws + 1836096);
    _Float16* Whi  = (_Float16*)(ws + 1852480);          // 8,192,000 f
    _Float16* Wlo  = (_Float16*)(ws + 10044480);

    k_convW2<<<dim3(500, 8), dim3(256), 0, stream>>>(LW, Whi, Wlo);
    k_init<<<dim3(128), dim3(256), 0, stream>>>(hA, cT, done);
    const float* hin = hA;
    float* hout = hB;
    for (int t = 0; t < TT; ++t) {
      const float* xin = (t == 0) ? features : x;
      k_gates<<<dim3(32, 8), dim3(256), 0, stream>>>(xin, hin, Wih, Whh, gatesP);
      k_lstm_update_frag<<<dim3(64), dim3(256), 0, stream>>>(gatesP, bih, bhh, cT, hout, hfh, hfl);
      k_logits4<<<dim3(500), dim3(256), 0, stream>>>((const f16x8*)Whi, (const f16x8*)Wlo,
                                                     (const f16x8*)hfh, (const f16x8*)hfl,
                                                     lb, keys[t][0], keys[t][1], pf4, pidx);
      k_sample2<<<dim3(64), dim3(256), 0, stream>>>(pf4, pidx, embW, done, x, out, t, 500);
      const float* tmp = hout; hout = (float*)hin; hin = tmp;
    }
  } else {
    // ---------------- mid path (r5 proven, ~6.4 MB) ----------------
    float*  gatesP = ws + 131072;
    float4* pf4    = (float4*)(ws + 131072 + 1048576);
    int*    pidx   = (int*)(ws + 131072 + 1048576 + 256000);
    int*    done   = (int*)(ws + 131072 + 1048576 + 256000 + 64000);

    k_init<<<dim3(128), dim3(256), 0, stream>>>(hA, cT, done);
    const float* hin = hA;
    float* hout = hB;
    for (int t = 0; t < TT; ++t) {
      const float* xin = (t == 0) ? features : x;
      k_gates<<<dim3(32, 8), dim3(256), 0, stream>>>(xin, hin, Wih, Whh, gatesP);
      k_lstm_update<<<dim3(64), dim3(256), 0, stream>>>(gatesP, bih, bhh, cT, hout);
      k_logits2<<<dim3(1000), dim3(128), 0, stream>>>(hout, LW, lb, keys[t][0], keys[t][1], pf4, pidx);
      k_sample2<<<dim3(64), dim3(256), 0, stream>>>(pf4, pidx, embW, done, x, out, t, 1000);
      const float* tmp = hout; hout = (float*)hin; hin = tmp;
    }
  }
}